// Round 5
// baseline (625.295 us; speedup 1.0000x reference)
//
#include <hip/hip_runtime.h>

#define NND 32768      // total nodes N = B*NNODES
#define NE  262144     // edges
#define HD 128
#define NPAIR 2048     // B*FEAS

__device__ __forceinline__ void fma4(float4& a, float s, const float4& w){
  a.x = fmaf(s, w.x, a.x);
  a.y = fmaf(s, w.y, a.y);
  a.z = fmaf(s, w.z, a.z);
  a.w = fmaf(s, w.w, a.w);
}

// ---------------- output zero-fill ----------------
__global__ __launch_bounds__(256) void k_zero(float4* __restrict__ p, int n4){
  int i = blockIdx.x*256 + threadIdx.x;
  int stride = gridDim.x*256;
  float4 z = make_float4(0.f,0.f,0.f,0.f);
  for (; i < n4; i += stride) p[i] = z;
}

// ---------------- CSR build ----------------
__global__ __launch_bounds__(256) void k_count(const int* __restrict__ dst, int* __restrict__ cnt){
  int e = blockIdx.x*256 + threadIdx.x;
  if (e < NE) atomicAdd(&cnt[dst[e]], 1);
}

__global__ __launch_bounds__(1024) void k_scan(const int* __restrict__ cnt, int* __restrict__ rowp,
                                               float* __restrict__ invdeg){
  __shared__ int part[1024];
  int t = threadIdx.x;
  int base = t*32;
  int local[32];
  int s = 0;
  #pragma unroll
  for (int j=0;j<32;j++){ local[j] = s; s += cnt[base+j]; }
  part[t] = s;
  __syncthreads();
  for (int d=1; d<1024; d<<=1){
    int v = (t>=d) ? part[t-d] : 0;
    __syncthreads();
    part[t] += v;
    __syncthreads();
  }
  int off = (t==0) ? 0 : part[t-1];
  #pragma unroll
  for (int j=0;j<32;j++){
    rowp[base+j] = off + local[j];
    int c = cnt[base+j];
    invdeg[base+j] = 1.0f / (float)(c > 0 ? c : 1);
  }
  if (t == 1023) rowp[NND] = off + s;
}

__global__ __launch_bounds__(256) void k_fill(const int* __restrict__ src, const int* __restrict__ dst,
                                              const int* __restrict__ rowp, int* __restrict__ fillc,
                                              int* __restrict__ csr){
  int e = blockIdx.x*256 + threadIdx.x;
  if (e < NE){
    int d = dst[e];
    int p = atomicAdd(&fillc[d], 1);
    csr[rowp[d] + p] = src[e];
  }
}

// ---------------- layer-0 aggregation (IN=8) ----------------
__global__ __launch_bounds__(256) void k_agg8(const float* __restrict__ x, const int* __restrict__ rowp,
                                              const int* __restrict__ csr, const float* __restrict__ invdeg,
                                              float* __restrict__ z8){
  int i = blockIdx.x*256 + threadIdx.x;
  float s[8] = {0,0,0,0,0,0,0,0};
  int a = rowp[i], bnd = rowp[i+1];
  for (int k=a;k<bnd;k++){
    int j = csr[k];
    const float4* p = (const float4*)&x[(size_t)j*8];
    float4 u0 = p[0], u1 = p[1];
    s[0]+=u0.x; s[1]+=u0.y; s[2]+=u0.z; s[3]+=u0.w;
    s[4]+=u1.x; s[5]+=u1.y; s[6]+=u1.z; s[7]+=u1.w;
  }
  float iv = invdeg[i];
  const float4* xp = (const float4*)&x[(size_t)i*8];
  float4 x0 = xp[0], x1 = xp[1];
  float4 o0, o1;
  o0.x = x0.x + s[0]*iv; o0.y = x0.y + s[1]*iv; o0.z = x0.z + s[2]*iv; o0.w = x0.w + s[3]*iv;
  o1.x = x1.x + s[4]*iv; o1.y = x1.y + s[5]*iv; o1.z = x1.z + s[6]*iv; o1.w = x1.w + s[7]*iv;
  ((float4*)&z8[(size_t)i*8])[0] = o0;
  ((float4*)&z8[(size_t)i*8])[1] = o1;
}

// ============================ fused GIN layers ============================
// raw = relu( relu(z @ W1 + b1) @ W2 + b2 ) with BN col-stats.
// Intermediate t kept TRANSPOSED in LDS: tT[k][row], stride 132, so phase-2
// A-reads are the same broadcast float4 pattern as the r3 GEMM (compiled+verified).

// layers 1..3 (K=128)
__global__ __launch_bounds__(256) void k_ginL(const float* __restrict__ A, const float* __restrict__ W1,
                                              const float* __restrict__ b1, const float* __restrict__ W2,
                                              const float* __restrict__ b2, float* __restrict__ C,
                                              float* __restrict__ part){
  __shared__ float zs[32*132];   // phase1 A staging [kk][row]
  __shared__ float ws[32*128];   // W staging [kk][col]
  __shared__ float tT[128*132];  // intermediate, transposed [k][row]
  const int K = 128;
  int tid = threadIdx.x;
  int r0 = blockIdx.x * 128;
  int tc = tid & 15, tr = tid >> 4;
  int c0 = tc*4;
  float4 acc[8][2];
  #pragma unroll
  for (int j=0;j<8;j++){ acc[j][0] = make_float4(0,0,0,0); acc[j][1] = make_float4(0,0,0,0); }
  float4 pa[4], pw[4];
  #pragma unroll
  for (int u=0;u<4;u++){
    int e = tid + u*256;
    pa[u] = *(const float4*)&A[(size_t)(r0 + (e>>3))*K + ((e&7)<<2)];
    pw[u] = *(const float4*)&W1[(size_t)(e>>5)*HD + ((e&31)<<2)];
  }
  for (int k0 = 0; k0 < K; k0 += 32){
    __syncthreads();
    #pragma unroll
    for (int u=0;u<4;u++){
      int e = tid + u*256;
      int row = e>>3, kc = (e&7)<<2;
      zs[(kc+0)*132 + row] = pa[u].x;
      zs[(kc+1)*132 + row] = pa[u].y;
      zs[(kc+2)*132 + row] = pa[u].z;
      zs[(kc+3)*132 + row] = pa[u].w;
      *(float4*)&ws[(e>>5)*HD + ((e&31)<<2)] = pw[u];
    }
    __syncthreads();
    if (k0 + 32 < K){
      #pragma unroll
      for (int u=0;u<4;u++){
        int e = tid + u*256;
        pa[u] = *(const float4*)&A[(size_t)(r0 + (e>>3))*K + (k0+32) + ((e&7)<<2)];
        pw[u] = *(const float4*)&W1[(size_t)((k0+32) + (e>>5))*HD + ((e&31)<<2)];
      }
    }
    #pragma unroll
    for (int kk=0; kk<32; kk++){
      float4 a0 = *(const float4*)&zs[kk*132 + tr*8];
      float4 a1 = *(const float4*)&zs[kk*132 + tr*8 + 4];
      float4 w0 = *(const float4*)&ws[kk*HD + c0];
      float4 w1 = *(const float4*)&ws[kk*HD + c0 + 64];
      fma4(acc[0][0], a0.x, w0); fma4(acc[0][1], a0.x, w1);
      fma4(acc[1][0], a0.y, w0); fma4(acc[1][1], a0.y, w1);
      fma4(acc[2][0], a0.z, w0); fma4(acc[2][1], a0.z, w1);
      fma4(acc[3][0], a0.w, w0); fma4(acc[3][1], a0.w, w1);
      fma4(acc[4][0], a1.x, w0); fma4(acc[4][1], a1.x, w1);
      fma4(acc[5][0], a1.y, w0); fma4(acc[5][1], a1.y, w1);
      fma4(acc[6][0], a1.z, w0); fma4(acc[6][1], a1.z, w1);
      fma4(acc[7][0], a1.w, w0); fma4(acc[7][1], a1.w, w1);
    }
  }
  // t = relu(acc + b1), stored transposed
  {
    float4 bA = *(const float4*)&b1[c0];
    float4 bB = *(const float4*)&b1[c0+64];
    #pragma unroll
    for (int j=0;j<8;j++){
      int row = tr*8 + j;
      float4 v0 = acc[j][0], v1 = acc[j][1];
      v0.x = fmaxf(v0.x + bA.x, 0.f); v0.y = fmaxf(v0.y + bA.y, 0.f);
      v0.z = fmaxf(v0.z + bA.z, 0.f); v0.w = fmaxf(v0.w + bA.w, 0.f);
      v1.x = fmaxf(v1.x + bB.x, 0.f); v1.y = fmaxf(v1.y + bB.y, 0.f);
      v1.z = fmaxf(v1.z + bB.z, 0.f); v1.w = fmaxf(v1.w + bB.w, 0.f);
      tT[(c0+0)*132 + row] = v0.x; tT[(c0+1)*132 + row] = v0.y;
      tT[(c0+2)*132 + row] = v0.z; tT[(c0+3)*132 + row] = v0.w;
      tT[(c0+64)*132 + row] = v1.x; tT[(c0+65)*132 + row] = v1.y;
      tT[(c0+66)*132 + row] = v1.z; tT[(c0+67)*132 + row] = v1.w;
    }
  }
  // phase 2: raw = relu(t @ W2 + b2)
  #pragma unroll
  for (int j=0;j<8;j++){ acc[j][0] = make_float4(0,0,0,0); acc[j][1] = make_float4(0,0,0,0); }
  #pragma unroll
  for (int u=0;u<4;u++){
    int e = tid + u*256;
    pw[u] = *(const float4*)&W2[(size_t)(e>>5)*HD + ((e&31)<<2)];
  }
  for (int k0 = 0; k0 < HD; k0 += 32){
    __syncthreads();
    #pragma unroll
    for (int u=0;u<4;u++){
      int e = tid + u*256;
      *(float4*)&ws[(e>>5)*HD + ((e&31)<<2)] = pw[u];
    }
    __syncthreads();
    if (k0 + 32 < HD){
      #pragma unroll
      for (int u=0;u<4;u++){
        int e = tid + u*256;
        pw[u] = *(const float4*)&W2[(size_t)((k0+32) + (e>>5))*HD + ((e&31)<<2)];
      }
    }
    #pragma unroll
    for (int kk=0; kk<32; kk++){
      float4 a0 = *(const float4*)&tT[(k0+kk)*132 + tr*8];
      float4 a1 = *(const float4*)&tT[(k0+kk)*132 + tr*8 + 4];
      float4 w0 = *(const float4*)&ws[kk*HD + c0];
      float4 w1 = *(const float4*)&ws[kk*HD + c0 + 64];
      fma4(acc[0][0], a0.x, w0); fma4(acc[0][1], a0.x, w1);
      fma4(acc[1][0], a0.y, w0); fma4(acc[1][1], a0.y, w1);
      fma4(acc[2][0], a0.z, w0); fma4(acc[2][1], a0.z, w1);
      fma4(acc[3][0], a0.w, w0); fma4(acc[3][1], a0.w, w1);
      fma4(acc[4][0], a1.x, w0); fma4(acc[4][1], a1.x, w1);
      fma4(acc[5][0], a1.y, w0); fma4(acc[5][1], a1.y, w1);
      fma4(acc[6][0], a1.z, w0); fma4(acc[6][1], a1.z, w1);
      fma4(acc[7][0], a1.w, w0); fma4(acc[7][1], a1.w, w1);
    }
  }
  float4 b0 = *(const float4*)&b2[c0];
  float4 b1v = *(const float4*)&b2[c0+64];
  float4 s0 = make_float4(0,0,0,0), s1 = s0, q0 = s0, q1 = s0;
  __syncthreads();   // all ws/tT reads done before zs/ws reuse as stats scratch
  #pragma unroll
  for (int j=0;j<8;j++){
    int row = r0 + tr*8 + j;
    float4 v0 = acc[j][0], v1 = acc[j][1];
    v0.x = fmaxf(v0.x + b0.x, 0.f); v0.y = fmaxf(v0.y + b0.y, 0.f);
    v0.z = fmaxf(v0.z + b0.z, 0.f); v0.w = fmaxf(v0.w + b0.w, 0.f);
    v1.x = fmaxf(v1.x + b1v.x, 0.f); v1.y = fmaxf(v1.y + b1v.y, 0.f);
    v1.z = fmaxf(v1.z + b1v.z, 0.f); v1.w = fmaxf(v1.w + b1v.w, 0.f);
    *(float4*)&C[(size_t)row*HD + c0] = v0;
    *(float4*)&C[(size_t)row*HD + c0 + 64] = v1;
    s0.x += v0.x; s0.y += v0.y; s0.z += v0.z; s0.w += v0.w;
    s1.x += v1.x; s1.y += v1.y; s1.z += v1.z; s1.w += v1.w;
    q0.x = fmaf(v0.x,v0.x,q0.x); q0.y = fmaf(v0.y,v0.y,q0.y);
    q0.z = fmaf(v0.z,v0.z,q0.z); q0.w = fmaf(v0.w,v0.w,q0.w);
    q1.x = fmaf(v1.x,v1.x,q1.x); q1.y = fmaf(v1.y,v1.y,q1.y);
    q1.z = fmaf(v1.z,v1.z,q1.z); q1.w = fmaf(v1.w,v1.w,q1.w);
  }
  *(float4*)&zs[tr*HD + c0]      = s0;
  *(float4*)&zs[tr*HD + c0 + 64] = s1;
  *(float4*)&ws[tr*HD + c0]      = q0;
  *(float4*)&ws[tr*HD + c0 + 64] = q1;
  __syncthreads();
  if (tid < HD){
    float s = 0.f, q = 0.f;
    #pragma unroll
    for (int u=0;u<16;u++){ s += zs[u*HD + tid]; q += ws[u*HD + tid]; }
    part[blockIdx.x*HD + tid] = s;
    part[256*HD + blockIdx.x*HD + tid] = q;
  }
}

// layer 0 (K=8 first matmul)
__global__ __launch_bounds__(256) void k_gin0(const float* __restrict__ A, const float* __restrict__ W1,
                                              const float* __restrict__ b1, const float* __restrict__ W2,
                                              const float* __restrict__ b2, float* __restrict__ C,
                                              float* __restrict__ part){
  __shared__ float zs[32*132];
  __shared__ float ws[32*128];
  __shared__ float tT[128*132];
  int tid = threadIdx.x;
  int r0 = blockIdx.x * 128;
  int tc = tid & 15, tr = tid >> 4;
  int c0 = tc*4;
  // stage z8 tile [128][8] (stride 9) and W1 [8][128]
  {
    int row = tid >> 1, half = (tid & 1) * 4;
    float4 v = *(const float4*)&A[(size_t)(r0 + row)*8 + half];
    zs[row*9 + half + 0] = v.x; zs[row*9 + half + 1] = v.y;
    zs[row*9 + half + 2] = v.z; zs[row*9 + half + 3] = v.w;
    int kk = tid >> 5, cc = (tid & 31) << 2;
    *(float4*)&ws[kk*HD + cc] = *(const float4*)&W1[(size_t)kk*HD + cc];
  }
  __syncthreads();
  float4 acc[8][2];
  #pragma unroll
  for (int j=0;j<8;j++){ acc[j][0] = make_float4(0,0,0,0); acc[j][1] = make_float4(0,0,0,0); }
  #pragma unroll
  for (int kk=0; kk<8; kk++){
    float4 w0 = *(const float4*)&ws[kk*HD + c0];
    float4 w1 = *(const float4*)&ws[kk*HD + c0 + 64];
    #pragma unroll
    for (int j=0;j<8;j++){
      float a = zs[(tr*8+j)*9 + kk];
      fma4(acc[j][0], a, w0); fma4(acc[j][1], a, w1);
    }
  }
  {
    float4 bA = *(const float4*)&b1[c0];
    float4 bB = *(const float4*)&b1[c0+64];
    #pragma unroll
    for (int j=0;j<8;j++){
      int row = tr*8 + j;
      float4 v0 = acc[j][0], v1 = acc[j][1];
      v0.x = fmaxf(v0.x + bA.x, 0.f); v0.y = fmaxf(v0.y + bA.y, 0.f);
      v0.z = fmaxf(v0.z + bA.z, 0.f); v0.w = fmaxf(v0.w + bA.w, 0.f);
      v1.x = fmaxf(v1.x + bB.x, 0.f); v1.y = fmaxf(v1.y + bB.y, 0.f);
      v1.z = fmaxf(v1.z + bB.z, 0.f); v1.w = fmaxf(v1.w + bB.w, 0.f);
      tT[(c0+0)*132 + row] = v0.x; tT[(c0+1)*132 + row] = v0.y;
      tT[(c0+2)*132 + row] = v0.z; tT[(c0+3)*132 + row] = v0.w;
      tT[(c0+64)*132 + row] = v1.x; tT[(c0+65)*132 + row] = v1.y;
      tT[(c0+66)*132 + row] = v1.z; tT[(c0+67)*132 + row] = v1.w;
    }
  }
  // phase 2 (identical to k_ginL's)
  #pragma unroll
  for (int j=0;j<8;j++){ acc[j][0] = make_float4(0,0,0,0); acc[j][1] = make_float4(0,0,0,0); }
  float4 pw[4];
  #pragma unroll
  for (int u=0;u<4;u++){
    int e = tid + u*256;
    pw[u] = *(const float4*)&W2[(size_t)(e>>5)*HD + ((e&31)<<2)];
  }
  for (int k0 = 0; k0 < HD; k0 += 32){
    __syncthreads();
    #pragma unroll
    for (int u=0;u<4;u++){
      int e = tid + u*256;
      *(float4*)&ws[(e>>5)*HD + ((e&31)<<2)] = pw[u];
    }
    __syncthreads();
    if (k0 + 32 < HD){
      #pragma unroll
      for (int u=0;u<4;u++){
        int e = tid + u*256;
        pw[u] = *(const float4*)&W2[(size_t)((k0+32) + (e>>5))*HD + ((e&31)<<2)];
      }
    }
    #pragma unroll
    for (int kk=0; kk<32; kk++){
      float4 a0 = *(const float4*)&tT[(k0+kk)*132 + tr*8];
      float4 a1 = *(const float4*)&tT[(k0+kk)*132 + tr*8 + 4];
      float4 w0 = *(const float4*)&ws[kk*HD + c0];
      float4 w1 = *(const float4*)&ws[kk*HD + c0 + 64];
      fma4(acc[0][0], a0.x, w0); fma4(acc[0][1], a0.x, w1);
      fma4(acc[1][0], a0.y, w0); fma4(acc[1][1], a0.y, w1);
      fma4(acc[2][0], a0.z, w0); fma4(acc[2][1], a0.z, w1);
      fma4(acc[3][0], a0.w, w0); fma4(acc[3][1], a0.w, w1);
      fma4(acc[4][0], a1.x, w0); fma4(acc[4][1], a1.x, w1);
      fma4(acc[5][0], a1.y, w0); fma4(acc[5][1], a1.y, w1);
      fma4(acc[6][0], a1.z, w0); fma4(acc[6][1], a1.z, w1);
      fma4(acc[7][0], a1.w, w0); fma4(acc[7][1], a1.w, w1);
    }
  }
  float4 b0 = *(const float4*)&b2[c0];
  float4 b1v = *(const float4*)&b2[c0+64];
  float4 s0 = make_float4(0,0,0,0), s1 = s0, q0 = s0, q1 = s0;
  __syncthreads();
  #pragma unroll
  for (int j=0;j<8;j++){
    int row = r0 + tr*8 + j;
    float4 v0 = acc[j][0], v1 = acc[j][1];
    v0.x = fmaxf(v0.x + b0.x, 0.f); v0.y = fmaxf(v0.y + b0.y, 0.f);
    v0.z = fmaxf(v0.z + b0.z, 0.f); v0.w = fmaxf(v0.w + b0.w, 0.f);
    v1.x = fmaxf(v1.x + b1v.x, 0.f); v1.y = fmaxf(v1.y + b1v.y, 0.f);
    v1.z = fmaxf(v1.z + b1v.z, 0.f); v1.w = fmaxf(v1.w + b1v.w, 0.f);
    *(float4*)&C[(size_t)row*HD + c0] = v0;
    *(float4*)&C[(size_t)row*HD + c0 + 64] = v1;
    s0.x += v0.x; s0.y += v0.y; s0.z += v0.z; s0.w += v0.w;
    s1.x += v1.x; s1.y += v1.y; s1.z += v1.z; s1.w += v1.w;
    q0.x = fmaf(v0.x,v0.x,q0.x); q0.y = fmaf(v0.y,v0.y,q0.y);
    q0.z = fmaf(v0.z,v0.z,q0.z); q0.w = fmaf(v0.w,v0.w,q0.w);
    q1.x = fmaf(v1.x,v1.x,q1.x); q1.y = fmaf(v1.y,v1.y,q1.y);
    q1.z = fmaf(v1.z,v1.z,q1.z); q1.w = fmaf(v1.w,v1.w,q1.w);
  }
  *(float4*)&zs[tr*HD + c0]      = s0;
  *(float4*)&zs[tr*HD + c0 + 64] = s1;
  *(float4*)&ws[tr*HD + c0]      = q0;
  *(float4*)&ws[tr*HD + c0 + 64] = q1;
  __syncthreads();
  if (tid < HD){
    float s = 0.f, q = 0.f;
    #pragma unroll
    for (int u=0;u<16;u++){ s += zs[u*HD + tid]; q += ws[u*HD + tid]; }
    part[blockIdx.x*HD + tid] = s;
    part[256*HD + blockIdx.x*HD + tid] = q;
  }
}

// ---------------- BN finalize ----------------
__global__ __launch_bounds__(128) void k_bn_fin(const float* __restrict__ part, const float* __restrict__ gamma,
                                                const float* __restrict__ beta, float* __restrict__ scale,
                                                float* __restrict__ shift){
  int f = threadIdx.x;
  float s = 0.f, q = 0.f;
  for (int b=0;b<256;b++){ s += part[b*HD+f]; q += part[256*HD + b*HD + f]; }
  float mu  = s * (1.0f/NND);
  float var = q * (1.0f/NND) - mu*mu;
  float sc  = gamma[f] * rsqrtf(var + 1e-5f);
  scale[f] = sc;
  shift[f] = beta[f] - mu*sc;
}

// ---------------- fused: BN-apply (folded) + mean-aggregate + npool accumulate ----------------
__global__ __launch_bounds__(128) void k_agg_bn(const float* __restrict__ raw, const int* __restrict__ rowp,
                                                const int* __restrict__ csr, const float* __restrict__ invdeg,
                                                const float* __restrict__ scale, const float* __restrict__ shift,
                                                float* __restrict__ z, float* __restrict__ npool, int first){
  int i = blockIdx.x;
  int f = threadIdx.x;
  int a = rowp[i], bnd = rowp[i+1];
  float s = 0.f;
  for (int k = a; k < bnd; k++) s += raw[(size_t)csr[k]*HD + f];
  float sc = scale[f], sh = shift[f];
  size_t idx = (size_t)i*HD + f;
  float vi = fmaf(raw[idx], sc, sh);
  float zz = vi + fmaf(invdeg[i]*sc, s, (bnd > a) ? sh : 0.f);
  z[idx] = zz;
  npool[idx] = first ? vi : (npool[idx] + vi);
}

// final layer: npool += BN(raw), and per-batch column sums of npool -> gsum
__global__ __launch_bounds__(256) void k_bn_acc2(const float* __restrict__ raw, const float* __restrict__ scale,
                                                 const float* __restrict__ shift, float* __restrict__ npool,
                                                 float* __restrict__ gsum){
  __shared__ float red[8*128];
  int tid = threadIdx.x;
  int r0 = blockIdx.x * 32;               // 1024 blocks, same batch per block
  int c = (tid & 31) * 4;
  int rg = tid >> 5;                      // 0..7
  float4 sc = *(const float4*)&scale[c];
  float4 sh = *(const float4*)&shift[c];
  float4 s = make_float4(0,0,0,0);
  #pragma unroll
  for (int u=0;u<4;u++){
    int row = r0 + rg + 8*u;
    size_t idx = (size_t)row*HD + c;
    float4 r = *(const float4*)&raw[idx];
    float4 np = *(const float4*)&npool[idx];
    float4 v;
    v.x = fmaf(r.x, sc.x, sh.x); v.y = fmaf(r.y, sc.y, sh.y);
    v.z = fmaf(r.z, sc.z, sh.z); v.w = fmaf(r.w, sc.w, sh.w);
    np.x += v.x; np.y += v.y; np.z += v.z; np.w += v.w;
    *(float4*)&npool[idx] = np;
    s.x += np.x; s.y += np.y; s.z += np.z; s.w += np.w;
  }
  *(float4*)&red[rg*128 + c] = s;
  __syncthreads();
  if (tid < 32){
    int c2 = tid*4;
    float4 acc = make_float4(0,0,0,0);
    #pragma unroll
    for (int g=0; g<8; g++){
      float4 v = *(const float4*)&red[g*128 + c2];
      acc.x += v.x; acc.y += v.y; acc.z += v.z; acc.w += v.w;
    }
    int b = r0 >> 10;
    atomicAdd(&gsum[b*HD + c2+0], acc.x);
    atomicAdd(&gsum[b*HD + c2+1], acc.y);
    atomicAdd(&gsum[b*HD + c2+2], acc.z);
    atomicAdd(&gsum[b*HD + c2+3], acc.w);
  }
}

// ---------------- policy path (selected 4096 node instances) ----------------
__global__ __launch_bounds__(256) void k_build_aug(const int* __restrict__ mrows, const int* __restrict__ mcols,
                                                   const float* __restrict__ npool, const float* __restrict__ gsum,
                                                   float* __restrict__ aug){
  int idx = blockIdx.x;
  int t = threadIdx.x;
  int j = idx & 2047;
  int rg = mrows[j];
  int b = rg >> 10;
  int g = (idx >= 2048) ? ((b << 10) | mcols[j]) : rg;
  float v;
  if (t < 128) v = npool[(size_t)g*HD + t];
  else         v = gsum[b*HD + (t-128)] * (1.0f/1024.0f);
  aug[(size_t)idx*256 + t] = v;
}

// fused policy layer: C = tanh(A@W1+b1)@W2+b2.  64-row tile, T kept in LDS. (r3-proven)
template<int K1>
__global__ __launch_bounds__(256) void k_pol(const float* __restrict__ A, const float* __restrict__ W1,
                                             const float* __restrict__ b1, const float* __restrict__ W2,
                                             const float* __restrict__ b2, float* __restrict__ C){
  __shared__ float S1[32*128 + 64*36];
  __shared__ float T[64*132];
  int tid = threadIdx.x;
  int r0 = blockIdx.x * 64;
  int tc = tid & 15, rg = tid >> 4;
  int c0 = tc * 4;
  float4 acc0[4], acc1[4];
  #pragma unroll
  for (int j=0;j<4;j++){ acc0[j] = make_float4(0,0,0,0); acc1[j] = make_float4(0,0,0,0); }
  for (int k0 = 0; k0 < K1; k0 += 32){
    __syncthreads();
    #pragma unroll
    for (int u=0;u<4;u++){
      int e = tid + u*256;
      *(float4*)&S1[(e>>5)*HD + ((e&31)<<2)] = *(const float4*)&W1[(size_t)(k0 + (e>>5))*HD + ((e&31)<<2)];
    }
    #pragma unroll
    for (int u=0;u<2;u++){
      int e = tid + u*256;
      *(float4*)&S1[4096 + (e>>3)*36 + ((e&7)<<2)] = *(const float4*)&A[(size_t)(r0 + (e>>3))*K1 + k0 + ((e&7)<<2)];
    }
    __syncthreads();
    #pragma unroll
    for (int kk=0; kk<32; kk+=4){
      float4 w0[4], w1[4];
      #pragma unroll
      for (int q=0;q<4;q++){
        w0[q] = *(const float4*)&S1[(kk+q)*HD + c0];
        w1[q] = *(const float4*)&S1[(kk+q)*HD + c0 + 64];
      }
      #pragma unroll
      for (int j=0;j<4;j++){
        float4 av = *(const float4*)&S1[4096 + (rg+16*j)*36 + kk];
        fma4(acc0[j], av.x, w0[0]); fma4(acc1[j], av.x, w1[0]);
        fma4(acc0[j], av.y, w0[1]); fma4(acc1[j], av.y, w1[1]);
        fma4(acc0[j], av.z, w0[2]); fma4(acc1[j], av.z, w1[2]);
        fma4(acc0[j], av.w, w0[3]); fma4(acc1[j], av.w, w1[3]);
      }
    }
  }
  {
    float4 bA = *(const float4*)&b1[c0];
    float4 bB = *(const float4*)&b1[c0+64];
    #pragma unroll
    for (int j=0;j<4;j++){
      int r = rg + 16*j;
      float4 v0 = acc0[j], v1 = acc1[j];
      v0.x = tanhf(v0.x + bA.x); v0.y = tanhf(v0.y + bA.y);
      v0.z = tanhf(v0.z + bA.z); v0.w = tanhf(v0.w + bA.w);
      v1.x = tanhf(v1.x + bB.x); v1.y = tanhf(v1.y + bB.y);
      v1.z = tanhf(v1.z + bB.z); v1.w = tanhf(v1.w + bB.w);
      *(float4*)&T[r*132 + c0] = v0;
      *(float4*)&T[r*132 + c0 + 64] = v1;
    }
  }
  float4 d0[4], d1[4];
  #pragma unroll
  for (int j=0;j<4;j++){ d0[j] = make_float4(0,0,0,0); d1[j] = make_float4(0,0,0,0); }
  for (int k0 = 0; k0 < HD; k0 += 32){
    __syncthreads();
    #pragma unroll
    for (int u=0;u<4;u++){
      int e = tid + u*256;
      *(float4*)&S1[(e>>5)*HD + ((e&31)<<2)] = *(const float4*)&W2[(size_t)(k0 + (e>>5))*HD + ((e&31)<<2)];
    }
    __syncthreads();
    #pragma unroll
    for (int kk=0; kk<32; kk+=4){
      float4 w0[4], w1[4];
      #pragma unroll
      for (int q=0;q<4;q++){
        w0[q] = *(const float4*)&S1[(kk+q)*HD + c0];
        w1[q] = *(const float4*)&S1[(kk+q)*HD + c0 + 64];
      }
      #pragma unroll
      for (int j=0;j<4;j++){
        float4 av = *(const float4*)&T[(rg+16*j)*132 + k0 + kk];
        fma4(d0[j], av.x, w0[0]); fma4(d1[j], av.x, w1[0]);
        fma4(d0[j], av.y, w0[1]); fma4(d1[j], av.y, w1[1]);
        fma4(d0[j], av.z, w0[2]); fma4(d1[j], av.z, w1[2]);
        fma4(d0[j], av.w, w0[3]); fma4(d1[j], av.w, w1[3]);
      }
    }
  }
  float4 bA = *(const float4*)&b2[c0];
  float4 bB = *(const float4*)&b2[c0+64];
  #pragma unroll
  for (int j=0;j<4;j++){
    int row = r0 + rg + 16*j;
    float4 v0 = d0[j], v1 = d1[j];
    v0.x += bA.x; v0.y += bA.y; v0.z += bA.z; v0.w += bA.w;
    v1.x += bB.x; v1.y += bB.y; v1.z += bB.z; v1.w += bB.w;
    *(float4*)&C[(size_t)row*HD + c0] = v0;
    *(float4*)&C[(size_t)row*HD + c0 + 64] = v1;
  }
}

// score + per-batch sparse softmax (dedup of repeated cells) + scatter
__global__ __launch_bounds__(64) void k_score(const float* __restrict__ Z, const int* __restrict__ mrows,
                                              const int* __restrict__ mcols, float* __restrict__ out){
  __shared__ int rr[64]; __shared__ int cc[64]; __shared__ float red[64];
  int b = blockIdx.x, f = threadIdx.x;
  int i = b*64 + f;
  int rg = mrows[i];
  int row = rg & 1023;
  int col = mcols[i];
  const float4* zr = (const float4*)&Z[(size_t)i*HD];
  const float4* zc = (const float4*)&Z[(size_t)(NPAIR + i)*HD];
  float s = 0.f;
  #pragma unroll
  for (int k=0;k<32;k++){
    float4 a = zr[k], c = zc[k];
    s = fmaf(a.x,c.x, fmaf(a.y,c.y, fmaf(a.z,c.z, fmaf(a.w,c.w, s))));
  }
  rr[f]=row; cc[f]=col; red[f]=s;
  __syncthreads();
  for (int d=32; d>0; d>>=1){
    if (f<d) red[f] = fmaxf(red[f], red[f+d]);
    __syncthreads();
  }
  float m = red[0];
  __syncthreads();
  bool first = true;
  for (int j=0;j<f;j++) if (rr[j]==row && cc[j]==col) first = false;
  float e = expf(s - m);
  red[f] = first ? e : 0.0f;
  __syncthreads();
  for (int d=32; d>0; d>>=1){
    if (f<d) red[f] += red[f+d];
    __syncthreads();
  }
  float denom = red[0];
  out[(size_t)b*1048576 + row*1024 + col] = e / denom;
}

extern "C" void kernel_launch(void* const* d_in, const int* in_sizes, int n_in,
                              void* d_out, int out_size, void* d_ws, size_t ws_size,
                              hipStream_t stream){
  const float* x     = (const float*)d_in[0];
  const int*   ei    = (const int*)d_in[1];
  const int*   mrows = (const int*)d_in[3];
  const int*   mcols = (const int*)d_in[4];
  const float* g0w1  = (const float*)d_in[5];
  const float* g0b1  = (const float*)d_in[6];
  const float* g0w2  = (const float*)d_in[7];
  const float* g0b2  = (const float*)d_in[8];
  const float* gw1   = (const float*)d_in[9];
  const float* gb1   = (const float*)d_in[10];
  const float* gw2   = (const float*)d_in[11];
  const float* gb2   = (const float*)d_in[12];
  const float* bng   = (const float*)d_in[13];
  const float* bnb   = (const float*)d_in[14];
  const float* p0w1  = (const float*)d_in[15];
  const float* p0b1  = (const float*)d_in[16];
  const float* p0w2  = (const float*)d_in[17];
  const float* p0b2  = (const float*)d_in[18];
  const float* pw1   = (const float*)d_in[19];
  const float* pb1   = (const float*)d_in[20];
  const float* pw2   = (const float*)d_in[21];
  const float* pb2   = (const float*)d_in[22];

  float* fw    = (float*)d_ws;
  float* bufRaw= fw;                        // N*H
  float* bufZ  = fw + 4194304;              // N*H
  float* npool = fw + 8388608;              // N*H
  float* aug   = fw + 12582912;             // 4096*256
  float* pX    = fw + 13631488;             // 4096*128
  float* pY    = fw + 14155776;             // 4096*128
  float* pZ    = fw + 14680064;             // 4096*128
  float* z8    = fw + 15204352;             // N*8
  float* invdeg= fw + 15466496;             // N
  float* bnsc  = fw + 15499264;             // H
  float* bnsh  = fw + 15499392;             // H
  float* part  = fw + 15499520;             // 2*256*H
  int*   cnt   = (int*)(fw + 15565056);     // N
  int*   fillc = cnt + NND;                 // N
  float* gsum  = (float*)(fillc + NND);     // B*H
  int*   rowp  = (int*)(gsum + 4096);       // N+1
  int*   csr   = rowp + NND + 1;            // E

  const int* src = ei;
  const int* dst = ei + NE;

  hipLaunchKernelGGL(k_zero, dim3(2048), dim3(256), 0, stream, (float4*)d_out, out_size/4);
  hipMemsetAsync(cnt, 0, (size_t)(NND + NND + 4096)*4, stream);   // cnt, fillc, gsum

  hipLaunchKernelGGL(k_count, dim3(NE/256), dim3(256), 0, stream, dst, cnt);
  hipLaunchKernelGGL(k_scan, dim3(1), dim3(1024), 0, stream, cnt, rowp, invdeg);
  hipLaunchKernelGGL(k_fill, dim3(NE/256), dim3(256), 0, stream, src, dst, rowp, fillc, csr);

  // layer 0 (fused MLP)
  hipLaunchKernelGGL(k_agg8, dim3(NND/256), dim3(256), 0, stream, x, rowp, csr, invdeg, z8);
  hipLaunchKernelGGL(k_gin0, dim3(NND/128), dim3(256), 0, stream, z8, g0w1, g0b1, g0w2, g0b2, bufRaw, part);
  hipLaunchKernelGGL(k_bn_fin, dim3(1), dim3(128), 0, stream, part, bng, bnb, bnsc, bnsh);

  // layers 1..3 (fused MLP per layer)
  for (int l=0;l<3;l++){
    hipLaunchKernelGGL(k_agg_bn, dim3(NND), dim3(128), 0, stream, bufRaw, rowp, csr, invdeg,
                       bnsc, bnsh, bufZ, npool, (l==0) ? 1 : 0);
    hipLaunchKernelGGL(k_ginL, dim3(NND/128), dim3(256), 0, stream, bufZ, gw1 + l*16384, gb1 + l*128,
                       gw2 + l*16384, gb2 + l*128, bufRaw, part);
    hipLaunchKernelGGL(k_bn_fin, dim3(1), dim3(128), 0, stream, part, bng + (l+1)*128, bnb + (l+1)*128, bnsc, bnsh);
  }
  // layer 3's npool contribution + per-batch gsum
  hipLaunchKernelGGL(k_bn_acc2, dim3(NND/32), dim3(256), 0, stream, bufRaw, bnsc, bnsh, npool, gsum);

  // policy on the 4096 referenced node instances only
  hipLaunchKernelGGL(k_build_aug, dim3(4096), dim3(256), 0, stream, mrows, mcols, npool, gsum, aug);
  hipLaunchKernelGGL((k_pol<256>), dim3(64), dim3(256), 0, stream, aug, p0w1, p0b1, p0w2, p0b2, pX);
  hipLaunchKernelGGL((k_pol<128>), dim3(64), dim3(256), 0, stream, pX, pw1, pb1, pw2, pb2, pY);
  hipLaunchKernelGGL((k_pol<128>), dim3(64), dim3(256), 0, stream, pY, pw1 + 16384, pb1 + 128, pw2 + 16384, pb2 + 128, pZ);

  hipLaunchKernelGGL(k_score, dim3(32), dim3(64), 0, stream, pZ, mrows, mcols, (float*)d_out);
}

// Round 6
// 529.827 us; speedup vs baseline: 1.1802x; 1.1802x over previous
//
#include <hip/hip_runtime.h>

#define NND 32768      // total nodes N = B*NNODES
#define NE  262144     // edges
#define HD 128
#define NPAIR 2048     // B*FEAS
#define NBLK 512       // gemm64 blocks (NND/64)
#define SQOFF 65536    // NBLK*128, sqsum offset within a part slot
#define PSLOT 131072   // 2*NBLK*128, per-layer part slot

__device__ __forceinline__ void fma4(float4& a, float s, const float4& w){
  a.x = fmaf(s, w.x, a.x);
  a.y = fmaf(s, w.y, a.y);
  a.z = fmaf(s, w.z, a.z);
  a.w = fmaf(s, w.w, a.w);
}

// ---------------- output zero-fill ----------------
__global__ __launch_bounds__(256) void k_zero(float4* __restrict__ p, int n4){
  int i = blockIdx.x*256 + threadIdx.x;
  int stride = gridDim.x*256;
  float4 z = make_float4(0.f,0.f,0.f,0.f);
  for (; i < n4; i += stride) p[i] = z;
}

// ---------------- CSR build ----------------
__global__ __launch_bounds__(256) void k_count(const int* __restrict__ dst, int* __restrict__ cnt){
  int e = blockIdx.x*256 + threadIdx.x;
  if (e < NE) atomicAdd(&cnt[dst[e]], 1);
}

__global__ __launch_bounds__(1024) void k_scan(const int* __restrict__ cnt, int* __restrict__ rowp,
                                               float* __restrict__ invdeg){
  __shared__ int part[1024];
  int t = threadIdx.x;
  int base = t*32;
  int local[32];
  int s = 0;
  #pragma unroll
  for (int j=0;j<32;j++){ local[j] = s; s += cnt[base+j]; }
  part[t] = s;
  __syncthreads();
  for (int d=1; d<1024; d<<=1){
    int v = (t>=d) ? part[t-d] : 0;
    __syncthreads();
    part[t] += v;
    __syncthreads();
  }
  int off = (t==0) ? 0 : part[t-1];
  #pragma unroll
  for (int j=0;j<32;j++){
    rowp[base+j] = off + local[j];
    int c = cnt[base+j];
    invdeg[base+j] = 1.0f / (float)(c > 0 ? c : 1);
  }
  if (t == 1023) rowp[NND] = off + s;
}

__global__ __launch_bounds__(256) void k_fill(const int* __restrict__ src, const int* __restrict__ dst,
                                              const int* __restrict__ rowp, int* __restrict__ fillc,
                                              int* __restrict__ csr){
  int e = blockIdx.x*256 + threadIdx.x;
  if (e < NE){
    int d = dst[e];
    int p = atomicAdd(&fillc[d], 1);
    csr[rowp[d] + p] = src[e];
  }
}

// ---------------- layer-0 aggregation (IN=8) ----------------
__global__ __launch_bounds__(256) void k_agg8(const float* __restrict__ x, const int* __restrict__ rowp,
                                              const int* __restrict__ csr, const float* __restrict__ invdeg,
                                              float* __restrict__ z8){
  int i = blockIdx.x*256 + threadIdx.x;
  float s[8] = {0,0,0,0,0,0,0,0};
  int a = rowp[i], bnd = rowp[i+1];
  for (int k=a;k<bnd;k++){
    int j = csr[k];
    const float4* p = (const float4*)&x[(size_t)j*8];
    float4 u0 = p[0], u1 = p[1];
    s[0]+=u0.x; s[1]+=u0.y; s[2]+=u0.z; s[3]+=u0.w;
    s[4]+=u1.x; s[5]+=u1.y; s[6]+=u1.z; s[7]+=u1.w;
  }
  float iv = invdeg[i];
  const float4* xp = (const float4*)&x[(size_t)i*8];
  float4 x0 = xp[0], x1 = xp[1];
  float4 o0, o1;
  o0.x = x0.x + s[0]*iv; o0.y = x0.y + s[1]*iv; o0.z = x0.z + s[2]*iv; o0.w = x0.w + s[3]*iv;
  o1.x = x1.x + s[4]*iv; o1.y = x1.y + s[5]*iv; o1.z = x1.z + s[6]*iv; o1.w = x1.w + s[7]*iv;
  ((float4*)&z8[(size_t)i*8])[0] = o0;
  ((float4*)&z8[(size_t)i*8])[1] = o1;
}

// [N x 8] @ [8 x 128] + bias, ReLU
__global__ __launch_bounds__(256) void k_gemm8(const float* __restrict__ A, const float* __restrict__ W,
                                               const float* __restrict__ bias, float* __restrict__ C){
  __shared__ float Ws[8*HD];
  __shared__ float bs[HD];
  int tid = threadIdx.x;
  for (int u=tid; u<8*HD; u+=256) Ws[u] = W[u];
  if (tid < HD) bs[tid] = bias[tid];
  __syncthreads();
  int g = blockIdx.x*256 + tid;     // over NND*HD
  int row = g >> 7, c = g & 127;
  const float4* a4 = (const float4*)&A[(size_t)row*8];
  float4 a0 = a4[0], a1 = a4[1];
  float s = bs[c];
  s = fmaf(a0.x, Ws[0*128+c], s); s = fmaf(a0.y, Ws[1*128+c], s);
  s = fmaf(a0.z, Ws[2*128+c], s); s = fmaf(a0.w, Ws[3*128+c], s);
  s = fmaf(a1.x, Ws[4*128+c], s); s = fmaf(a1.y, Ws[5*128+c], s);
  s = fmaf(a1.z, Ws[6*128+c], s); s = fmaf(a1.w, Ws[7*128+c], s);
  C[g] = fmaxf(s, 0.0f);
}

// ---------------- main GEMM: [N x 128] @ [128 x 128] + bias + ReLU (+BN col stats) ----------------
// 64-row x 128-col tile, 256 threads, 512 blocks (2 blocks/CU): the R1-proven occupancy shape.
// thread: c0=(tid&15)*4 (cols c0, c0+64), rg=tid>>4 (rows rg+16j, j=0..3).
template<int STATS>
__global__ __launch_bounds__(256) void k_gemm64(const float* __restrict__ A, const float* __restrict__ W,
                                                const float* __restrict__ bias, float* __restrict__ C,
                                                float* __restrict__ part){
  __shared__ float Ws[64*128];
  __shared__ float As[64*68];     // padded stride 68
  const int K = 128;
  int tid = threadIdx.x;
  int r0 = blockIdx.x * 64;
  int c0 = (tid & 15) * 4;
  int rg = tid >> 4;
  float4 acc0[4], acc1[4];
  #pragma unroll
  for (int j=0;j<4;j++){ acc0[j] = make_float4(0,0,0,0); acc1[j] = make_float4(0,0,0,0); }
  for (int k0=0;k0<K;k0+=64){
    #pragma unroll
    for (int u=0;u<8;u++){
      int e = tid + u*256;
      int kk = e >> 5, cc = (e & 31) << 2;
      *(float4*)&Ws[kk*128+cc] = *(const float4*)&W[(size_t)(k0+kk)*128 + cc];
    }
    #pragma unroll
    for (int u=0;u<4;u++){
      int e = tid + u*256;
      int r = e >> 4, cc = (e & 15) << 2;
      *(float4*)&As[r*68+cc] = *(const float4*)&A[(size_t)(r0+r)*K + k0 + cc];
    }
    __syncthreads();
    #pragma unroll
    for (int kk=0; kk<64; kk+=4){
      float4 w0[4], w1[4];
      #pragma unroll
      for (int q=0;q<4;q++){
        w0[q] = *(const float4*)&Ws[(kk+q)*128 + c0];
        w1[q] = *(const float4*)&Ws[(kk+q)*128 + c0 + 64];
      }
      #pragma unroll
      for (int j=0;j<4;j++){
        float4 av = *(const float4*)&As[(rg + 16*j)*68 + kk];
        fma4(acc0[j], av.x, w0[0]); fma4(acc1[j], av.x, w1[0]);
        fma4(acc0[j], av.y, w0[1]); fma4(acc1[j], av.y, w1[1]);
        fma4(acc0[j], av.z, w0[2]); fma4(acc1[j], av.z, w1[2]);
        fma4(acc0[j], av.w, w0[3]); fma4(acc1[j], av.w, w1[3]);
      }
    }
    __syncthreads();
  }
  float4 bA = *(const float4*)&bias[c0];
  float4 bB = *(const float4*)&bias[c0+64];
  float4 s0 = make_float4(0,0,0,0), s1 = s0, q0 = s0, q1 = s0;
  #pragma unroll
  for (int j=0;j<4;j++){
    int row = r0 + rg + 16*j;
    float4 v0 = acc0[j], v1 = acc1[j];
    v0.x = fmaxf(v0.x + bA.x, 0.f); v0.y = fmaxf(v0.y + bA.y, 0.f);
    v0.z = fmaxf(v0.z + bA.z, 0.f); v0.w = fmaxf(v0.w + bA.w, 0.f);
    v1.x = fmaxf(v1.x + bB.x, 0.f); v1.y = fmaxf(v1.y + bB.y, 0.f);
    v1.z = fmaxf(v1.z + bB.z, 0.f); v1.w = fmaxf(v1.w + bB.w, 0.f);
    *(float4*)&C[(size_t)row*HD + c0] = v0;
    *(float4*)&C[(size_t)row*HD + c0 + 64] = v1;
    if (STATS){
      s0.x += v0.x; s0.y += v0.y; s0.z += v0.z; s0.w += v0.w;
      s1.x += v1.x; s1.y += v1.y; s1.z += v1.z; s1.w += v1.w;
      q0.x = fmaf(v0.x,v0.x,q0.x); q0.y = fmaf(v0.y,v0.y,q0.y);
      q0.z = fmaf(v0.z,v0.z,q0.z); q0.w = fmaf(v0.w,v0.w,q0.w);
      q1.x = fmaf(v1.x,v1.x,q1.x); q1.y = fmaf(v1.y,v1.y,q1.y);
      q1.z = fmaf(v1.z,v1.z,q1.z); q1.w = fmaf(v1.w,v1.w,q1.w);
    }
  }
  if (STATS){
    // last loop iter ended with __syncthreads(); safe to reuse Ws/As as scratch
    *(float4*)&Ws[rg*128 + c0]      = s0;
    *(float4*)&Ws[rg*128 + c0 + 64] = s1;
    *(float4*)&As[rg*128 + c0]      = q0;
    *(float4*)&As[rg*128 + c0 + 64] = q1;
    __syncthreads();
    if (tid < HD){
      float s = 0.f, q = 0.f;
      #pragma unroll
      for (int u=0;u<16;u++){ s += Ws[u*128 + tid]; q += As[u*128 + tid]; }
      part[blockIdx.x*HD + tid] = s;
      part[SQOFF + blockIdx.x*HD + tid] = q;
    }
  }
}

// ---------------- BN finalize (per layer slot) ----------------
__global__ __launch_bounds__(128) void k_bn_fin(const float* __restrict__ part, const float* __restrict__ gamma,
                                                const float* __restrict__ beta, float* __restrict__ scale,
                                                float* __restrict__ shift){
  int f = threadIdx.x;
  float s = 0.f, q = 0.f;
  for (int b=0;b<NBLK;b++){ s += part[b*HD+f]; q += part[SQOFF + b*HD + f]; }
  float mu  = s * (1.0f/NND);
  float var = q * (1.0f/NND) - mu*mu;
  float sc  = gamma[f] * rsqrtf(var + 1e-5f);
  scale[f] = sc;
  shift[f] = beta[f] - mu*sc;
}

// ---------------- fused: BN-apply (folded) + mean-aggregate ----------------
// one block per node (max TLP for the random gather).
__global__ __launch_bounds__(128) void k_agg_bn(const float* __restrict__ raw, const int* __restrict__ rowp,
                                                const int* __restrict__ csr, const float* __restrict__ invdeg,
                                                const float* __restrict__ scale, const float* __restrict__ shift,
                                                float* __restrict__ z){
  int i = blockIdx.x;
  int f = threadIdx.x;
  int a = rowp[i], bnd = rowp[i+1];
  float s = 0.f;
  for (int k = a; k < bnd; k++) s += raw[(size_t)csr[k]*HD + f];
  float sc = scale[f], sh = shift[f];
  size_t idx = (size_t)i*HD + f;
  float vi = fmaf(raw[idx], sc, sh);
  z[idx] = vi + fmaf(invdeg[i]*sc, s, (bnd > a) ? sh : 0.f);
}

// ---------------- gpool from per-block part colsums ----------------
// gsum[b][f] = sum_l ( sc_l[f]*sum_{16 blocks of b} part_l + 1024*sh_l[f] )
__global__ __launch_bounds__(128) void k_gpool(const float* __restrict__ part, const float* __restrict__ bnsc,
                                               const float* __restrict__ bnsh, float* __restrict__ gsum){
  int b = blockIdx.x, f = threadIdx.x;
  float g = 0.f;
  #pragma unroll
  for (int l=0;l<4;l++){
    float s = 0.f;
    #pragma unroll
    for (int t=0;t<16;t++) s += part[l*PSLOT + (b*16 + t)*HD + f];
    g += fmaf(bnsc[l*128+f], s, 1024.0f*bnsh[l*128+f]);
  }
  gsum[b*HD + f] = g;
}

// ---------------- build aug rows (npool on the fly from raw0..raw3) ----------------
__global__ __launch_bounds__(256) void k_build_aug(const int* __restrict__ mrows, const int* __restrict__ mcols,
                                                   const float* __restrict__ raw0, const float* __restrict__ raw1,
                                                   const float* __restrict__ raw2, const float* __restrict__ raw3,
                                                   const float* __restrict__ bnsc, const float* __restrict__ bnsh,
                                                   const float* __restrict__ gsum, float* __restrict__ aug){
  int idx = blockIdx.x;     // 0..4095: first 2048 = row nodes, next 2048 = col nodes
  int t = threadIdx.x;
  int j = idx & 2047;
  int rg = mrows[j];
  int b = rg >> 10;
  int g = (idx >= 2048) ? ((b << 10) | mcols[j]) : rg;
  float v;
  if (t < 128){
    size_t o = (size_t)g*HD + t;
    v = fmaf(bnsc[t],     raw0[o], bnsh[t]);
    v = fmaf(bnsc[128+t], raw1[o], v + bnsh[128+t]);
    v = fmaf(bnsc[256+t], raw2[o], v + bnsh[256+t]);
    v = fmaf(bnsc[384+t], raw3[o], v + bnsh[384+t]);
  } else {
    v = gsum[b*HD + (t-128)] * (1.0f/1024.0f);
  }
  aug[(size_t)idx*256 + t] = v;
}

// fused policy layer: C = tanh(A@W1+b1)@W2+b2.  64-row tile (r3/r5-proven).
template<int K1>
__global__ __launch_bounds__(256) void k_pol(const float* __restrict__ A, const float* __restrict__ W1,
                                             const float* __restrict__ b1, const float* __restrict__ W2,
                                             const float* __restrict__ b2, float* __restrict__ C){
  __shared__ float S1[32*128 + 64*36];
  __shared__ float T[64*132];
  int tid = threadIdx.x;
  int r0 = blockIdx.x * 64;
  int tc = tid & 15, rg = tid >> 4;
  int c0 = tc * 4;
  float4 acc0[4], acc1[4];
  #pragma unroll
  for (int j=0;j<4;j++){ acc0[j] = make_float4(0,0,0,0); acc1[j] = make_float4(0,0,0,0); }
  for (int k0 = 0; k0 < K1; k0 += 32){
    __syncthreads();
    #pragma unroll
    for (int u=0;u<4;u++){
      int e = tid + u*256;
      *(float4*)&S1[(e>>5)*HD + ((e&31)<<2)] = *(const float4*)&W1[(size_t)(k0 + (e>>5))*HD + ((e&31)<<2)];
    }
    #pragma unroll
    for (int u=0;u<2;u++){
      int e = tid + u*256;
      *(float4*)&S1[4096 + (e>>3)*36 + ((e&7)<<2)] = *(const float4*)&A[(size_t)(r0 + (e>>3))*K1 + k0 + ((e&7)<<2)];
    }
    __syncthreads();
    #pragma unroll
    for (int kk=0; kk<32; kk+=4){
      float4 w0[4], w1[4];
      #pragma unroll
      for (int q=0;q<4;q++){
        w0[q] = *(const float4*)&S1[(kk+q)*HD + c0];
        w1[q] = *(const float4*)&S1[(kk+q)*HD + c0 + 64];
      }
      #pragma unroll
      for (int j=0;j<4;j++){
        float4 av = *(const float4*)&S1[4096 + (rg+16*j)*36 + kk];
        fma4(acc0[j], av.x, w0[0]); fma4(acc1[j], av.x, w1[0]);
        fma4(acc0[j], av.y, w0[1]); fma4(acc1[j], av.y, w1[1]);
        fma4(acc0[j], av.z, w0[2]); fma4(acc1[j], av.z, w1[2]);
        fma4(acc0[j], av.w, w0[3]); fma4(acc1[j], av.w, w1[3]);
      }
    }
  }
  {
    float4 bA = *(const float4*)&b1[c0];
    float4 bB = *(const float4*)&b1[c0+64];
    #pragma unroll
    for (int j=0;j<4;j++){
      int r = rg + 16*j;
      float4 v0 = acc0[j], v1 = acc1[j];
      v0.x = tanhf(v0.x + bA.x); v0.y = tanhf(v0.y + bA.y);
      v0.z = tanhf(v0.z + bA.z); v0.w = tanhf(v0.w + bA.w);
      v1.x = tanhf(v1.x + bB.x); v1.y = tanhf(v1.y + bB.y);
      v1.z = tanhf(v1.z + bB.z); v1.w = tanhf(v1.w + bB.w);
      *(float4*)&T[r*132 + c0] = v0;
      *(float4*)&T[r*132 + c0 + 64] = v1;
    }
  }
  float4 d0[4], d1[4];
  #pragma unroll
  for (int j=0;j<4;j++){ d0[j] = make_float4(0,0,0,0); d1[j] = make_float4(0,0,0,0); }
  for (int k0 = 0; k0 < HD; k0 += 32){
    __syncthreads();
    #pragma unroll
    for (int u=0;u<4;u++){
      int e = tid + u*256;
      *(float4*)&S1[(e>>5)*HD + ((e&31)<<2)] = *(const float4*)&W2[(size_t)(k0 + (e>>5))*HD + ((e&31)<<2)];
    }
    __syncthreads();
    #pragma unroll
    for (int kk=0; kk<32; kk+=4){
      float4 w0[4], w1[4];
      #pragma unroll
      for (int q=0;q<4;q++){
        w0[q] = *(const float4*)&S1[(kk+q)*HD + c0];
        w1[q] = *(const float4*)&S1[(kk+q)*HD + c0 + 64];
      }
      #pragma unroll
      for (int j=0;j<4;j++){
        float4 av = *(const float4*)&T[(rg+16*j)*132 + k0 + kk];
        fma4(d0[j], av.x, w0[0]); fma4(d1[j], av.x, w1[0]);
        fma4(d0[j], av.y, w0[1]); fma4(d1[j], av.y, w1[1]);
        fma4(d0[j], av.z, w0[2]); fma4(d1[j], av.z, w1[2]);
        fma4(d0[j], av.w, w0[3]); fma4(d1[j], av.w, w1[3]);
      }
    }
  }
  float4 bA = *(const float4*)&b2[c0];
  float4 bB = *(const float4*)&b2[c0+64];
  #pragma unroll
  for (int j=0;j<4;j++){
    int row = r0 + rg + 16*j;
    float4 v0 = d0[j], v1 = d1[j];
    v0.x += bA.x; v0.y += bA.y; v0.z += bA.z; v0.w += bA.w;
    v1.x += bB.x; v1.y += bB.y; v1.z += bB.z; v1.w += bB.w;
    *(float4*)&C[(size_t)row*HD + c0] = v0;
    *(float4*)&C[(size_t)row*HD + c0 + 64] = v1;
  }
}

// score + per-batch sparse softmax (dedup of repeated cells) + scatter
__global__ __launch_bounds__(64) void k_score(const float* __restrict__ Z, const int* __restrict__ mrows,
                                              const int* __restrict__ mcols, float* __restrict__ out){
  __shared__ int rr[64]; __shared__ int cc[64]; __shared__ float red[64];
  int b = blockIdx.x, f = threadIdx.x;
  int i = b*64 + f;
  int rg = mrows[i];
  int row = rg & 1023;
  int col = mcols[i];
  const float4* zr = (const float4*)&Z[(size_t)i*HD];
  const float4* zc = (const float4*)&Z[(size_t)(NPAIR + i)*HD];
  float s = 0.f;
  #pragma unroll
  for (int k=0;k<32;k++){
    float4 a = zr[k], c = zc[k];
    s = fmaf(a.x,c.x, fmaf(a.y,c.y, fmaf(a.z,c.z, fmaf(a.w,c.w, s))));
  }
  rr[f]=row; cc[f]=col; red[f]=s;
  __syncthreads();
  for (int d=32; d>0; d>>=1){
    if (f<d) red[f] = fmaxf(red[f], red[f+d]);
    __syncthreads();
  }
  float m = red[0];
  __syncthreads();
  bool first = true;
  for (int j=0;j<f;j++) if (rr[j]==row && cc[j]==col) first = false;
  float e = expf(s - m);
  red[f] = first ? e : 0.0f;
  __syncthreads();
  for (int d=32; d>0; d>>=1){
    if (f<d) red[f] += red[f+d];
    __syncthreads();
  }
  float denom = red[0];
  out[(size_t)b*1048576 + row*1024 + col] = e / denom;
}

extern "C" void kernel_launch(void* const* d_in, const int* in_sizes, int n_in,
                              void* d_out, int out_size, void* d_ws, size_t ws_size,
                              hipStream_t stream){
  const float* x     = (const float*)d_in[0];
  const int*   ei    = (const int*)d_in[1];
  const int*   mrows = (const int*)d_in[3];
  const int*   mcols = (const int*)d_in[4];
  const float* g0w1  = (const float*)d_in[5];
  const float* g0b1  = (const float*)d_in[6];
  const float* g0w2  = (const float*)d_in[7];
  const float* g0b2  = (const float*)d_in[8];
  const float* gw1   = (const float*)d_in[9];
  const float* gb1   = (const float*)d_in[10];
  const float* gw2   = (const float*)d_in[11];
  const float* gb2   = (const float*)d_in[12];
  const float* bng   = (const float*)d_in[13];
  const float* bnb   = (const float*)d_in[14];
  const float* p0w1  = (const float*)d_in[15];
  const float* p0b1  = (const float*)d_in[16];
  const float* p0w2  = (const float*)d_in[17];
  const float* p0b2  = (const float*)d_in[18];
  const float* pw1   = (const float*)d_in[19];
  const float* pb1   = (const float*)d_in[20];
  const float* pw2   = (const float*)d_in[21];
  const float* pb2   = (const float*)d_in[22];

  float* fw    = (float*)d_ws;
  float* bufT  = fw;                        // N*H (MLP intermediate)
  float* bufZ  = fw + 4194304;              // N*H (aggregated input)
  float* raw0  = fw + 8388608;              // N*H
  float* raw1  = fw + 12582912;             // N*H
  float* raw2  = fw + 16777216;             // N*H
  float* raw3  = fw + 20971520;             // N*H
  float* aug   = fw + 25165824;             // 4096*256
  float* pX    = fw + 26214400;             // 4096*128
  float* pY    = fw + 26738688;             // 4096*128
  float* pZ    = fw + 27262976;             // 4096*128
  float* z8    = fw + 27787264;             // N*8
  float* invdeg= fw + 28049408;             // N
  float* bnsc  = fw + 28082176;             // 4*128
  float* bnsh  = fw + 28082688;             // 4*128
  float* part  = fw + 28083200;             // 4*PSLOT
  float* gsum  = fw + 28607488;             // B*H
  int*   cnt   = (int*)(fw + 28611584);     // N
  int*   fillc = cnt + NND;                 // N
  int*   rowp  = fillc + NND;               // N+1
  int*   csr   = rowp + NND + 1;            // E
  float* raws[4] = {raw0, raw1, raw2, raw3};

  const int* src = ei;
  const int* dst = ei + NE;

  hipLaunchKernelGGL(k_zero, dim3(2048), dim3(256), 0, stream, (float4*)d_out, out_size/4);
  hipMemsetAsync(cnt, 0, (size_t)(2*NND)*4, stream);   // cnt, fillc

  hipLaunchKernelGGL(k_count, dim3(NE/256), dim3(256), 0, stream, dst, cnt);
  hipLaunchKernelGGL(k_scan, dim3(1), dim3(1024), 0, stream, cnt, rowp, invdeg);
  hipLaunchKernelGGL(k_fill, dim3(NE/256), dim3(256), 0, stream, src, dst, rowp, fillc, csr);

  // layer 0
  hipLaunchKernelGGL(k_agg8, dim3(NND/256), dim3(256), 0, stream, x, rowp, csr, invdeg, z8);
  hipLaunchKernelGGL(k_gemm8, dim3(NND*HD/256), dim3(256), 0, stream, z8, g0w1, g0b1, bufT);
  hipLaunchKernelGGL((k_gemm64<1>), dim3(NBLK), dim3(256), 0, stream, bufT, g0w2, g0b2, raw0, part);
  hipLaunchKernelGGL(k_bn_fin, dim3(1), dim3(128), 0, stream, part, bng, bnb, bnsc, bnsh);

  // layers 1..3
  for (int l=0;l<3;l++){
    hipLaunchKernelGGL(k_agg_bn, dim3(NND), dim3(128), 0, stream, raws[l], rowp, csr, invdeg,
                       bnsc + l*128, bnsh + l*128, bufZ);
    hipLaunchKernelGGL((k_gemm64<0>), dim3(NBLK), dim3(256), 0, stream, bufZ, gw1 + l*16384, gb1 + l*128, bufT, (float*)nullptr);
    hipLaunchKernelGGL((k_gemm64<1>), dim3(NBLK), dim3(256), 0, stream, bufT, gw2 + l*16384, gb2 + l*128, raws[l+1], part + (l+1)*PSLOT);
    hipLaunchKernelGGL(k_bn_fin, dim3(1), dim3(128), 0, stream, part + (l+1)*PSLOT, bng + (l+1)*128, bnb + (l+1)*128,
                       bnsc + (l+1)*128, bnsh + (l+1)*128);
  }

  // gpool from part colsums; npool on the fly in build_aug
  hipLaunchKernelGGL(k_gpool, dim3(32), dim3(128), 0, stream, part, bnsc, bnsh, gsum);
  hipLaunchKernelGGL(k_build_aug, dim3(4096), dim3(256), 0, stream, mrows, mcols,
                     raw0, raw1, raw2, raw3, bnsc, bnsh, gsum, aug);

  hipLaunchKernelGGL((k_pol<256>), dim3(64), dim3(256), 0, stream, aug, p0w1, p0b1, p0w2, p0b2, pX);
  hipLaunchKernelGGL((k_pol<128>), dim3(64), dim3(256), 0, stream, pX, pw1, pb1, pw2, pb2, pY);
  hipLaunchKernelGGL((k_pol<128>), dim3(64), dim3(256), 0, stream, pY, pw1 + 16384, pb1 + 128, pw2 + 16384, pb2 + 128, pZ);

  hipLaunchKernelGGL(k_score, dim3(32), dim3(64), 0, stream, pZ, mrows, mcols, (float*)d_out);
}

// Round 7
// 517.573 us; speedup vs baseline: 1.2081x; 1.0237x over previous
//
#include <hip/hip_runtime.h>

#define NND 32768      // total nodes N = B*NNODES
#define NE  262144     // edges
#define HD 128
#define NPAIR 2048     // B*FEAS
#define NBLK 256       // gemm128 blocks (NND/128)
#define SQOFF 32768    // NBLK*128, sqsum offset within a part slot
#define PSLOT 65536    // 2*NBLK*128, per-layer part slot

__device__ __forceinline__ void fma4(float4& a, float s, const float4& w){
  a.x = fmaf(s, w.x, a.x);
  a.y = fmaf(s, w.y, a.y);
  a.z = fmaf(s, w.z, a.z);
  a.w = fmaf(s, w.w, a.w);
}

// ---------------- output zero-fill ----------------
__global__ __launch_bounds__(256) void k_zero(float4* __restrict__ p, int n4){
  int i = blockIdx.x*256 + threadIdx.x;
  int stride = gridDim.x*256;
  float4 z = make_float4(0.f,0.f,0.f,0.f);
  for (; i < n4; i += stride) p[i] = z;
}

// ---------------- CSR build ----------------
__global__ __launch_bounds__(256) void k_count(const int* __restrict__ dst, int* __restrict__ cnt){
  int e = blockIdx.x*256 + threadIdx.x;
  if (e < NE) atomicAdd(&cnt[dst[e]], 1);
}

__global__ __launch_bounds__(1024) void k_scan(const int* __restrict__ cnt, int* __restrict__ rowp,
                                               float* __restrict__ invdeg){
  __shared__ int part[1024];
  int t = threadIdx.x;
  int base = t*32;
  int local[32];
  int s = 0;
  #pragma unroll
  for (int j=0;j<32;j++){ local[j] = s; s += cnt[base+j]; }
  part[t] = s;
  __syncthreads();
  for (int d=1; d<1024; d<<=1){
    int v = (t>=d) ? part[t-d] : 0;
    __syncthreads();
    part[t] += v;
    __syncthreads();
  }
  int off = (t==0) ? 0 : part[t-1];
  #pragma unroll
  for (int j=0;j<32;j++){
    rowp[base+j] = off + local[j];
    int c = cnt[base+j];
    invdeg[base+j] = 1.0f / (float)(c > 0 ? c : 1);
  }
  if (t == 1023) rowp[NND] = off + s;
}

__global__ __launch_bounds__(256) void k_fill(const int* __restrict__ src, const int* __restrict__ dst,
                                              const int* __restrict__ rowp, int* __restrict__ fillc,
                                              int* __restrict__ csr){
  int e = blockIdx.x*256 + threadIdx.x;
  if (e < NE){
    int d = dst[e];
    int p = atomicAdd(&fillc[d], 1);
    csr[rowp[d] + p] = src[e];
  }
}

// ---------------- layer-0 aggregation (IN=8) ----------------
__global__ __launch_bounds__(256) void k_agg8(const float* __restrict__ x, const int* __restrict__ rowp,
                                              const int* __restrict__ csr, const float* __restrict__ invdeg,
                                              float* __restrict__ z8){
  int i = blockIdx.x*256 + threadIdx.x;
  float s[8] = {0,0,0,0,0,0,0,0};
  int a = rowp[i], bnd = rowp[i+1];
  for (int k=a;k<bnd;k++){
    int j = csr[k];
    const float4* p = (const float4*)&x[(size_t)j*8];
    float4 u0 = p[0], u1 = p[1];
    s[0]+=u0.x; s[1]+=u0.y; s[2]+=u0.z; s[3]+=u0.w;
    s[4]+=u1.x; s[5]+=u1.y; s[6]+=u1.z; s[7]+=u1.w;
  }
  float iv = invdeg[i];
  const float4* xp = (const float4*)&x[(size_t)i*8];
  float4 x0 = xp[0], x1 = xp[1];
  float4 o0, o1;
  o0.x = x0.x + s[0]*iv; o0.y = x0.y + s[1]*iv; o0.z = x0.z + s[2]*iv; o0.w = x0.w + s[3]*iv;
  o1.x = x1.x + s[4]*iv; o1.y = x1.y + s[5]*iv; o1.z = x1.z + s[6]*iv; o1.w = x1.w + s[7]*iv;
  ((float4*)&z8[(size_t)i*8])[0] = o0;
  ((float4*)&z8[(size_t)i*8])[1] = o1;
}

// [N x 8] @ [8 x 128] + bias, ReLU
__global__ __launch_bounds__(256) void k_gemm8(const float* __restrict__ A, const float* __restrict__ W,
                                               const float* __restrict__ bias, float* __restrict__ C){
  __shared__ float Ws[8*HD];
  __shared__ float bs[HD];
  int tid = threadIdx.x;
  for (int u=tid; u<8*HD; u+=256) Ws[u] = W[u];
  if (tid < HD) bs[tid] = bias[tid];
  __syncthreads();
  int g = blockIdx.x*256 + tid;     // over NND*HD
  int row = g >> 7, c = g & 127;
  const float4* a4 = (const float4*)&A[(size_t)row*8];
  float4 a0 = a4[0], a1 = a4[1];
  float s = bs[c];
  s = fmaf(a0.x, Ws[0*128+c], s); s = fmaf(a0.y, Ws[1*128+c], s);
  s = fmaf(a0.z, Ws[2*128+c], s); s = fmaf(a0.w, Ws[3*128+c], s);
  s = fmaf(a1.x, Ws[4*128+c], s); s = fmaf(a1.y, Ws[5*128+c], s);
  s = fmaf(a1.z, Ws[6*128+c], s); s = fmaf(a1.w, Ws[7*128+c], s);
  C[g] = fmaxf(s, 0.0f);
}

// ---------------- main GEMM: [N x 128] @ [128 x 128] + bias + ReLU (+BN col stats) ----------------
// 128x128 tile, 256 threads, 8x8/thread (0.25 LDS-reads per fma4 — best ratio). R3-proven structure.
template<int STATS>
__global__ __launch_bounds__(256) void k_gemm128(const float* __restrict__ A, const float* __restrict__ W,
                                                 const float* __restrict__ bias, float* __restrict__ C,
                                                 float* __restrict__ part){
  __shared__ float At[32*132];   // [kk][row], stride 132
  __shared__ float Ws[32*128];   // [kk][col]
  const int K = 128;
  int tid = threadIdx.x;
  int r0 = blockIdx.x * 128;
  int tc = tid & 15, tr = tid >> 4;
  int c0 = tc * 4;               // cols c0..c0+3 and c0+64..c0+67
  float4 acc[8][2];
  #pragma unroll
  for (int j=0;j<8;j++){ acc[j][0] = make_float4(0,0,0,0); acc[j][1] = make_float4(0,0,0,0); }

  float4 pa[4], pw[4];
  #pragma unroll
  for (int u=0;u<4;u++){
    int e = tid + u*256;
    pa[u] = *(const float4*)&A[(size_t)(r0 + (e>>3))*K + ((e&7)<<2)];
    pw[u] = *(const float4*)&W[(size_t)(e>>5)*HD + ((e&31)<<2)];
  }
  for (int k0 = 0; k0 < K; k0 += 32){
    __syncthreads();
    #pragma unroll
    for (int u=0;u<4;u++){
      int e = tid + u*256;
      int row = e>>3, kc = (e&7)<<2;
      At[(kc+0)*132 + row] = pa[u].x;
      At[(kc+1)*132 + row] = pa[u].y;
      At[(kc+2)*132 + row] = pa[u].z;
      At[(kc+3)*132 + row] = pa[u].w;
      *(float4*)&Ws[(e>>5)*HD + ((e&31)<<2)] = pw[u];
    }
    __syncthreads();
    if (k0 + 32 < K){
      #pragma unroll
      for (int u=0;u<4;u++){
        int e = tid + u*256;
        pa[u] = *(const float4*)&A[(size_t)(r0 + (e>>3))*K + (k0+32) + ((e&7)<<2)];
        pw[u] = *(const float4*)&W[(size_t)((k0+32) + (e>>5))*HD + ((e&31)<<2)];
      }
    }
    #pragma unroll
    for (int kk=0; kk<32; kk++){
      float4 a0 = *(const float4*)&At[kk*132 + tr*8];
      float4 a1 = *(const float4*)&At[kk*132 + tr*8 + 4];
      float4 w0 = *(const float4*)&Ws[kk*HD + c0];
      float4 w1 = *(const float4*)&Ws[kk*HD + c0 + 64];
      fma4(acc[0][0], a0.x, w0); fma4(acc[0][1], a0.x, w1);
      fma4(acc[1][0], a0.y, w0); fma4(acc[1][1], a0.y, w1);
      fma4(acc[2][0], a0.z, w0); fma4(acc[2][1], a0.z, w1);
      fma4(acc[3][0], a0.w, w0); fma4(acc[3][1], a0.w, w1);
      fma4(acc[4][0], a1.x, w0); fma4(acc[4][1], a1.x, w1);
      fma4(acc[5][0], a1.y, w0); fma4(acc[5][1], a1.y, w1);
      fma4(acc[6][0], a1.z, w0); fma4(acc[6][1], a1.z, w1);
      fma4(acc[7][0], a1.w, w0); fma4(acc[7][1], a1.w, w1);
    }
  }
  float4 b0 = *(const float4*)&bias[c0];
  float4 b1 = *(const float4*)&bias[c0+64];
  float4 s0 = make_float4(0,0,0,0), s1 = s0, q0 = s0, q1 = s0;
  if (STATS) __syncthreads();     // all LDS reads done before reuse as stats scratch
  #pragma unroll
  for (int j=0;j<8;j++){
    int row = r0 + tr*8 + j;
    float4 v0 = acc[j][0], v1 = acc[j][1];
    v0.x = fmaxf(v0.x + b0.x, 0.f); v0.y = fmaxf(v0.y + b0.y, 0.f);
    v0.z = fmaxf(v0.z + b0.z, 0.f); v0.w = fmaxf(v0.w + b0.w, 0.f);
    v1.x = fmaxf(v1.x + b1.x, 0.f); v1.y = fmaxf(v1.y + b1.y, 0.f);
    v1.z = fmaxf(v1.z + b1.z, 0.f); v1.w = fmaxf(v1.w + b1.w, 0.f);
    *(float4*)&C[(size_t)row*HD + c0] = v0;
    *(float4*)&C[(size_t)row*HD + c0 + 64] = v1;
    if (STATS){
      s0.x += v0.x; s0.y += v0.y; s0.z += v0.z; s0.w += v0.w;
      s1.x += v1.x; s1.y += v1.y; s1.z += v1.z; s1.w += v1.w;
      q0.x = fmaf(v0.x,v0.x,q0.x); q0.y = fmaf(v0.y,v0.y,q0.y);
      q0.z = fmaf(v0.z,v0.z,q0.z); q0.w = fmaf(v0.w,v0.w,q0.w);
      q1.x = fmaf(v1.x,v1.x,q1.x); q1.y = fmaf(v1.y,v1.y,q1.y);
      q1.z = fmaf(v1.z,v1.z,q1.z); q1.w = fmaf(v1.w,v1.w,q1.w);
    }
  }
  if (STATS){
    *(float4*)&At[tr*HD + c0]      = s0;
    *(float4*)&At[tr*HD + c0 + 64] = s1;
    *(float4*)&Ws[tr*HD + c0]      = q0;
    *(float4*)&Ws[tr*HD + c0 + 64] = q1;
    __syncthreads();
    if (tid < HD){
      float s = 0.f, q = 0.f;
      #pragma unroll
      for (int t=0;t<16;t++){ s += At[t*HD + tid]; q += Ws[t*HD + tid]; }
      part[blockIdx.x*HD + tid] = s;
      part[SQOFF + blockIdx.x*HD + tid] = q;
    }
  }
}

// ---------------- BN finalize: one block per feature, parallel tree reduce ----------------
__global__ __launch_bounds__(256) void k_bn_fin(const float* __restrict__ part, const float* __restrict__ gamma,
                                                const float* __restrict__ beta, float* __restrict__ scale,
                                                float* __restrict__ shift){
  __shared__ float rs[256];
  __shared__ float rq[256];
  int f = blockIdx.x, t = threadIdx.x;
  rs[t] = part[t*HD + f];
  rq[t] = part[SQOFF + t*HD + f];
  __syncthreads();
  for (int d=128; d>0; d>>=1){
    if (t < d){ rs[t] += rs[t+d]; rq[t] += rq[t+d]; }
    __syncthreads();
  }
  if (t == 0){
    float mu  = rs[0] * (1.0f/NND);
    float var = rq[0] * (1.0f/NND) - mu*mu;
    float sc  = gamma[f] * rsqrtf(var + 1e-5f);
    scale[f] = sc;
    shift[f] = beta[f] - mu*sc;
  }
}

// ---------------- fused: BN-apply (folded) + mean-aggregate ----------------
__global__ __launch_bounds__(128) void k_agg_bn(const float* __restrict__ raw, const int* __restrict__ rowp,
                                                const int* __restrict__ csr, const float* __restrict__ invdeg,
                                                const float* __restrict__ scale, const float* __restrict__ shift,
                                                float* __restrict__ z){
  int i = blockIdx.x;
  int f = threadIdx.x;
  int a = rowp[i], bnd = rowp[i+1];
  float s = 0.f;
  for (int k = a; k < bnd; k++) s += raw[(size_t)csr[k]*HD + f];
  float sc = scale[f], sh = shift[f];
  size_t idx = (size_t)i*HD + f;
  float vi = fmaf(raw[idx], sc, sh);
  z[idx] = vi + fmaf(invdeg[i]*sc, s, (bnd > a) ? sh : 0.f);
}

// ---------------- gpool from per-block part colsums ----------------
// gsum[b][f] = sum_l ( sc_l[f]*sum_{8 blocks of b} part_l + 1024*sh_l[f] )
__global__ __launch_bounds__(128) void k_gpool(const float* __restrict__ part, const float* __restrict__ bnsc,
                                               const float* __restrict__ bnsh, float* __restrict__ gsum){
  int b = blockIdx.x, f = threadIdx.x;
  float g = 0.f;
  #pragma unroll
  for (int l=0;l<4;l++){
    float s = 0.f;
    #pragma unroll
    for (int t=0;t<8;t++) s += part[l*PSLOT + (b*8 + t)*HD + f];
    g += fmaf(bnsc[l*128+f], s, 1024.0f*bnsh[l*128+f]);
  }
  gsum[b*HD + f] = g;
}

// ---------------- build aug rows (npool on the fly from raw0..raw3) ----------------
__global__ __launch_bounds__(256) void k_build_aug(const int* __restrict__ mrows, const int* __restrict__ mcols,
                                                   const float* __restrict__ raw0, const float* __restrict__ raw1,
                                                   const float* __restrict__ raw2, const float* __restrict__ raw3,
                                                   const float* __restrict__ bnsc, const float* __restrict__ bnsh,
                                                   const float* __restrict__ gsum, float* __restrict__ aug){
  int idx = blockIdx.x;     // 0..4095: first 2048 = row nodes, next 2048 = col nodes
  int t = threadIdx.x;
  int j = idx & 2047;
  int rg = mrows[j];
  int b = rg >> 10;
  int g = (idx >= 2048) ? ((b << 10) | mcols[j]) : rg;
  float v;
  if (t < 128){
    size_t o = (size_t)g*HD + t;
    v = fmaf(bnsc[t],     raw0[o], bnsh[t]);
    v = fmaf(bnsc[128+t], raw1[o], v + bnsh[128+t]);
    v = fmaf(bnsc[256+t], raw2[o], v + bnsh[256+t]);
    v = fmaf(bnsc[384+t], raw3[o], v + bnsh[384+t]);
  } else {
    v = gsum[b*HD + (t-128)] * (1.0f/1024.0f);
  }
  aug[(size_t)idx*256 + t] = v;
}

// fused policy layer: C = tanh(A@W1+b1)@W2+b2.  64-row tile (r3/r5/r6-proven).
template<int K1>
__global__ __launch_bounds__(256) void k_pol(const float* __restrict__ A, const float* __restrict__ W1,
                                             const float* __restrict__ b1, const float* __restrict__ W2,
                                             const float* __restrict__ b2, float* __restrict__ C){
  __shared__ float S1[32*128 + 64*36];
  __shared__ float T[64*132];
  int tid = threadIdx.x;
  int r0 = blockIdx.x * 64;
  int tc = tid & 15, rg = tid >> 4;
  int c0 = tc * 4;
  float4 acc0[4], acc1[4];
  #pragma unroll
  for (int j=0;j<4;j++){ acc0[j] = make_float4(0,0,0,0); acc1[j] = make_float4(0,0,0,0); }
  for (int k0 = 0; k0 < K1; k0 += 32){
    __syncthreads();
    #pragma unroll
    for (int u=0;u<4;u++){
      int e = tid + u*256;
      *(float4*)&S1[(e>>5)*HD + ((e&31)<<2)] = *(const float4*)&W1[(size_t)(k0 + (e>>5))*HD + ((e&31)<<2)];
    }
    #pragma unroll
    for (int u=0;u<2;u++){
      int e = tid + u*256;
      *(float4*)&S1[4096 + (e>>3)*36 + ((e&7)<<2)] = *(const float4*)&A[(size_t)(r0 + (e>>3))*K1 + k0 + ((e&7)<<2)];
    }
    __syncthreads();
    #pragma unroll
    for (int kk=0; kk<32; kk+=4){
      float4 w0[4], w1[4];
      #pragma unroll
      for (int q=0;q<4;q++){
        w0[q] = *(const float4*)&S1[(kk+q)*HD + c0];
        w1[q] = *(const float4*)&S1[(kk+q)*HD + c0 + 64];
      }
      #pragma unroll
      for (int j=0;j<4;j++){
        float4 av = *(const float4*)&S1[4096 + (rg+16*j)*36 + kk];
        fma4(acc0[j], av.x, w0[0]); fma4(acc1[j], av.x, w1[0]);
        fma4(acc0[j], av.y, w0[1]); fma4(acc1[j], av.y, w1[1]);
        fma4(acc0[j], av.z, w0[2]); fma4(acc1[j], av.z, w1[2]);
        fma4(acc0[j], av.w, w0[3]); fma4(acc1[j], av.w, w1[3]);
      }
    }
  }
  {
    float4 bA = *(const float4*)&b1[c0];
    float4 bB = *(const float4*)&b1[c0+64];
    #pragma unroll
    for (int j=0;j<4;j++){
      int r = rg + 16*j;
      float4 v0 = acc0[j], v1 = acc1[j];
      v0.x = tanhf(v0.x + bA.x); v0.y = tanhf(v0.y + bA.y);
      v0.z = tanhf(v0.z + bA.z); v0.w = tanhf(v0.w + bA.w);
      v1.x = tanhf(v1.x + bB.x); v1.y = tanhf(v1.y + bB.y);
      v1.z = tanhf(v1.z + bB.z); v1.w = tanhf(v1.w + bB.w);
      *(float4*)&T[r*132 + c0] = v0;
      *(float4*)&T[r*132 + c0 + 64] = v1;
    }
  }
  float4 d0[4], d1[4];
  #pragma unroll
  for (int j=0;j<4;j++){ d0[j] = make_float4(0,0,0,0); d1[j] = make_float4(0,0,0,0); }
  for (int k0 = 0; k0 < HD; k0 += 32){
    __syncthreads();
    #pragma unroll
    for (int u=0;u<4;u++){
      int e = tid + u*256;
      *(float4*)&S1[(e>>5)*HD + ((e&31)<<2)] = *(const float4*)&W2[(size_t)(k0 + (e>>5))*HD + ((e&31)<<2)];
    }
    __syncthreads();
    #pragma unroll
    for (int kk=0; kk<32; kk+=4){
      float4 w0[4], w1[4];
      #pragma unroll
      for (int q=0;q<4;q++){
        w0[q] = *(const float4*)&S1[(kk+q)*HD + c0];
        w1[q] = *(const float4*)&S1[(kk+q)*HD + c0 + 64];
      }
      #pragma unroll
      for (int j=0;j<4;j++){
        float4 av = *(const float4*)&T[(rg+16*j)*132 + k0 + kk];
        fma4(d0[j], av.x, w0[0]); fma4(d1[j], av.x, w1[0]);
        fma4(d0[j], av.y, w0[1]); fma4(d1[j], av.y, w1[1]);
        fma4(d0[j], av.z, w0[2]); fma4(d1[j], av.z, w1[2]);
        fma4(d0[j], av.w, w0[3]); fma4(d1[j], av.w, w1[3]);
      }
    }
  }
  float4 bA = *(const float4*)&b2[c0];
  float4 bB = *(const float4*)&b2[c0+64];
  #pragma unroll
  for (int j=0;j<4;j++){
    int row = r0 + rg + 16*j;
    float4 v0 = d0[j], v1 = d1[j];
    v0.x += bA.x; v0.y += bA.y; v0.z += bA.z; v0.w += bA.w;
    v1.x += bB.x; v1.y += bB.y; v1.z += bB.z; v1.w += bB.w;
    *(float4*)&C[(size_t)row*HD + c0] = v0;
    *(float4*)&C[(size_t)row*HD + c0 + 64] = v1;
  }
}

// score + per-batch sparse softmax (dedup of repeated cells) + scatter
__global__ __launch_bounds__(64) void k_score(const float* __restrict__ Z, const int* __restrict__ mrows,
                                              const int* __restrict__ mcols, float* __restrict__ out){
  __shared__ int rr[64]; __shared__ int cc[64]; __shared__ float red[64];
  int b = blockIdx.x, f = threadIdx.x;
  int i = b*64 + f;
  int rg = mrows[i];
  int row = rg & 1023;
  int col = mcols[i];
  const float4* zr = (const float4*)&Z[(size_t)i*HD];
  const float4* zc = (const float4*)&Z[(size_t)(NPAIR + i)*HD];
  float s = 0.f;
  #pragma unroll
  for (int k=0;k<32;k++){
    float4 a = zr[k], c = zc[k];
    s = fmaf(a.x,c.x, fmaf(a.y,c.y, fmaf(a.z,c.z, fmaf(a.w,c.w, s))));
  }
  rr[f]=row; cc[f]=col; red[f]=s;
  __syncthreads();
  for (int d=32; d>0; d>>=1){
    if (f<d) red[f] = fmaxf(red[f], red[f+d]);
    __syncthreads();
  }
  float m = red[0];
  __syncthreads();
  bool first = true;
  for (int j=0;j<f;j++) if (rr[j]==row && cc[j]==col) first = false;
  float e = expf(s - m);
  red[f] = first ? e : 0.0f;
  __syncthreads();
  for (int d=32; d>0; d>>=1){
    if (f<d) red[f] += red[f+d];
    __syncthreads();
  }
  float denom = red[0];
  out[(size_t)b*1048576 + row*1024 + col] = e / denom;
}

extern "C" void kernel_launch(void* const* d_in, const int* in_sizes, int n_in,
                              void* d_out, int out_size, void* d_ws, size_t ws_size,
                              hipStream_t stream){
  const float* x     = (const float*)d_in[0];
  const int*   ei    = (const int*)d_in[1];
  const int*   mrows = (const int*)d_in[3];
  const int*   mcols = (const int*)d_in[4];
  const float* g0w1  = (const float*)d_in[5];
  const float* g0b1  = (const float*)d_in[6];
  const float* g0w2  = (const float*)d_in[7];
  const float* g0b2  = (const float*)d_in[8];
  const float* gw1   = (const float*)d_in[9];
  const float* gb1   = (const float*)d_in[10];
  const float* gw2   = (const float*)d_in[11];
  const float* gb2   = (const float*)d_in[12];
  const float* bng   = (const float*)d_in[13];
  const float* bnb   = (const float*)d_in[14];
  const float* p0w1  = (const float*)d_in[15];
  const float* p0b1  = (const float*)d_in[16];
  const float* p0w2  = (const float*)d_in[17];
  const float* p0b2  = (const float*)d_in[18];
  const float* pw1   = (const float*)d_in[19];
  const float* pb1   = (const float*)d_in[20];
  const float* pw2   = (const float*)d_in[21];
  const float* pb2   = (const float*)d_in[22];

  float* fw    = (float*)d_ws;
  float* bufT  = fw;                        // N*H (MLP intermediate)
  float* bufZ  = fw + 4194304;              // N*H (aggregated input)
  float* raw0  = fw + 8388608;              // N*H
  float* raw1  = fw + 12582912;             // N*H
  float* raw2  = fw + 16777216;             // N*H
  float* raw3  = fw + 20971520;             // N*H
  float* aug   = fw + 25165824;             // 4096*256
  float* pX    = fw + 26214400;             // 4096*128
  float* pY    = fw + 26738688;             // 4096*128
  float* pZ    = fw + 27262976;             // 4096*128
  float* z8    = fw + 27787264;             // N*8
  float* invdeg= fw + 28049408;             // N
  float* bnsc  = fw + 28082176;             // 4*128
  float* bnsh  = fw + 28082688;             // 4*128
  float* part  = fw + 28083200;             // 4*PSLOT
  float* gsum  = fw + 28607488;             // B*H
  int*   cnt   = (int*)(fw + 28611584);     // N
  int*   fillc = cnt + NND;                 // N
  int*   rowp  = fillc + NND;               // N+1
  int*   csr   = rowp + NND + 1;            // E
  float* raws[4] = {raw0, raw1, raw2, raw3};

  const int* src = ei;
  const int* dst = ei + NE;

  hipLaunchKernelGGL(k_zero, dim3(2048), dim3(256), 0, stream, (float4*)d_out, out_size/4);
  hipMemsetAsync(cnt, 0, (size_t)(2*NND)*4, stream);   // cnt, fillc

  hipLaunchKernelGGL(k_count, dim3(NE/256), dim3(256), 0, stream, dst, cnt);
  hipLaunchKernelGGL(k_scan, dim3(1), dim3(1024), 0, stream, cnt, rowp, invdeg);
  hipLaunchKernelGGL(k_fill, dim3(NE/256), dim3(256), 0, stream, src, dst, rowp, fillc, csr);

  // layer 0
  hipLaunchKernelGGL(k_agg8, dim3(NND/256), dim3(256), 0, stream, x, rowp, csr, invdeg, z8);
  hipLaunchKernelGGL(k_gemm8, dim3(NND*HD/256), dim3(256), 0, stream, z8, g0w1, g0b1, bufT);
  hipLaunchKernelGGL((k_gemm128<1>), dim3(NBLK), dim3(256), 0, stream, bufT, g0w2, g0b2, raw0, part);
  hipLaunchKernelGGL(k_bn_fin, dim3(128), dim3(256), 0, stream, part, bng, bnb, bnsc, bnsh);

  // layers 1..3
  for (int l=0;l<3;l++){
    hipLaunchKernelGGL(k_agg_bn, dim3(NND), dim3(128), 0, stream, raws[l], rowp, csr, invdeg,
                       bnsc + l*128, bnsh + l*128, bufZ);
    hipLaunchKernelGGL((k_gemm128<0>), dim3(NBLK), dim3(256), 0, stream, bufZ, gw1 + l*16384, gb1 + l*128, bufT, (float*)nullptr);
    hipLaunchKernelGGL((k_gemm128<1>), dim3(NBLK), dim3(256), 0, stream, bufT, gw2 + l*16384, gb2 + l*128, raws[l+1], part + (l+1)*PSLOT);
    hipLaunchKernelGGL(k_bn_fin, dim3(128), dim3(256), 0, stream, part + (l+1)*PSLOT, bng + (l+1)*128, bnb + (l+1)*128,
                       bnsc + (l+1)*128, bnsh + (l+1)*128);
  }

  // gpool from part colsums; npool on the fly in build_aug
  hipLaunchKernelGGL(k_gpool, dim3(32), dim3(128), 0, stream, part, bnsc, bnsh, gsum);
  hipLaunchKernelGGL(k_build_aug, dim3(4096), dim3(256), 0, stream, mrows, mcols,
                     raw0, raw1, raw2, raw3, bnsc, bnsh, gsum, aug);

  hipLaunchKernelGGL((k_pol<256>), dim3(64), dim3(256), 0, stream, aug, p0w1, p0b1, p0w2, p0b2, pX);
  hipLaunchKernelGGL((k_pol<128>), dim3(64), dim3(256), 0, stream, pX, pw1, pb1, pw2, pb2, pY);
  hipLaunchKernelGGL((k_pol<128>), dim3(64), dim3(256), 0, stream, pY, pw1 + 16384, pb1 + 128, pw2 + 16384, pb2 + 128, pZ);

  hipLaunchKernelGGL(k_score, dim3(32), dim3(64), 0, stream, pZ, mrows, mcols, (float*)d_out);
}

// Round 8
// 408.230 us; speedup vs baseline: 1.5317x; 1.2678x over previous
//
#include <hip/hip_runtime.h>

#define NND 32768      // total nodes N = B*NNODES
#define NE  262144     // edges
#define HD 128
#define NPAIR 2048     // B*FEAS
#define NBLK 256       // mgemm blocks (NND/128)
#define SQOFF 32768    // NBLK*128, sqsum offset within a part slot
#define PSLOT 65536    // 2*NBLK*128, per-layer part slot

typedef __attribute__((ext_vector_type(8))) short short8;
typedef __attribute__((ext_vector_type(4))) float f32x4;

__device__ __forceinline__ void fma4(float4& a, float s, const float4& w){
  a.x = fmaf(s, w.x, a.x);
  a.y = fmaf(s, w.y, a.y);
  a.z = fmaf(s, w.z, a.z);
  a.w = fmaf(s, w.w, a.w);
}

__device__ __forceinline__ unsigned short bf16rne(float x){
  unsigned int u = __float_as_uint(x);
  unsigned int r = u + 0x7FFFu + ((u >> 16) & 1u);
  return (unsigned short)(r >> 16);
}
__device__ __forceinline__ float bf16tof(unsigned short h){
  return __uint_as_float(((unsigned int)h) << 16);
}

// ---------------- output zero-fill ----------------
__global__ __launch_bounds__(256) void k_zero(float4* __restrict__ p, int n4){
  int i = blockIdx.x*256 + threadIdx.x;
  int stride = gridDim.x*256;
  float4 z = make_float4(0.f,0.f,0.f,0.f);
  for (; i < n4; i += stride) p[i] = z;
}

// ---------------- weight split+transpose: W[k][n] fp32 -> WT{hi,lo}[n][k] bf16 ----------------
__global__ __launch_bounds__(256) void k_wsplit(const float* __restrict__ g0w2, const float* __restrict__ gw1,
                                                const float* __restrict__ gw2, unsigned short* __restrict__ WThi,
                                                unsigned short* __restrict__ WTlo){
  __shared__ float tile[16*129];
  int kblk = blockIdx.x, mat = blockIdx.y;
  int k0 = kblk * 16;
  const float* W = (mat == 0) ? g0w2 : ((mat < 4) ? (gw1 + (mat-1)*16384) : (gw2 + (mat-4)*16384));
  int t = threadIdx.x;
  {
    int kk = t >> 4, n0 = (t & 15) * 8;
    float4 v0 = *(const float4*)&W[(size_t)(k0+kk)*HD + n0];
    float4 v1 = *(const float4*)&W[(size_t)(k0+kk)*HD + n0 + 4];
    tile[kk*129 + n0+0] = v0.x; tile[kk*129 + n0+1] = v0.y;
    tile[kk*129 + n0+2] = v0.z; tile[kk*129 + n0+3] = v0.w;
    tile[kk*129 + n0+4] = v1.x; tile[kk*129 + n0+5] = v1.y;
    tile[kk*129 + n0+6] = v1.z; tile[kk*129 + n0+7] = v1.w;
  }
  __syncthreads();
  int n = t >> 1, koff = (t & 1) * 8;
  short8 hv, lv;
  #pragma unroll
  for (int q=0;q<8;q++){
    float v = tile[(koff+q)*129 + n];
    unsigned short h = bf16rne(v);
    hv[q] = (short)h;
    lv[q] = (short)bf16rne(v - bf16tof(h));
  }
  size_t o = (size_t)mat*16384 + (size_t)n*HD + k0 + koff;
  *(short8*)&WThi[o] = hv;
  *(short8*)&WTlo[o] = lv;
}

// ---------------- CSR build ----------------
__global__ __launch_bounds__(256) void k_count(const int* __restrict__ dst, int* __restrict__ cnt){
  int e = blockIdx.x*256 + threadIdx.x;
  if (e < NE) atomicAdd(&cnt[dst[e]], 1);
}

__global__ __launch_bounds__(1024) void k_scan(const int* __restrict__ cnt, int* __restrict__ rowp,
                                               float* __restrict__ invdeg){
  __shared__ int part[1024];
  int t = threadIdx.x;
  int base = t*32;
  int local[32];
  int s = 0;
  #pragma unroll
  for (int j=0;j<32;j++){ local[j] = s; s += cnt[base+j]; }
  part[t] = s;
  __syncthreads();
  for (int d=1; d<1024; d<<=1){
    int v = (t>=d) ? part[t-d] : 0;
    __syncthreads();
    part[t] += v;
    __syncthreads();
  }
  int off = (t==0) ? 0 : part[t-1];
  #pragma unroll
  for (int j=0;j<32;j++){
    rowp[base+j] = off + local[j];
    int c = cnt[base+j];
    invdeg[base+j] = 1.0f / (float)(c > 0 ? c : 1);
  }
  if (t == 1023) rowp[NND] = off + s;
}

__global__ __launch_bounds__(256) void k_fill(const int* __restrict__ src, const int* __restrict__ dst,
                                              const int* __restrict__ rowp, int* __restrict__ fillc,
                                              int* __restrict__ csr){
  int e = blockIdx.x*256 + threadIdx.x;
  if (e < NE){
    int d = dst[e];
    int p = atomicAdd(&fillc[d], 1);
    csr[rowp[d] + p] = src[e];
  }
}

// ---------------- layer-0 aggregation (IN=8) ----------------
__global__ __launch_bounds__(256) void k_agg8(const float* __restrict__ x, const int* __restrict__ rowp,
                                              const int* __restrict__ csr, const float* __restrict__ invdeg,
                                              float* __restrict__ z8){
  int i = blockIdx.x*256 + threadIdx.x;
  float s[8] = {0,0,0,0,0,0,0,0};
  int a = rowp[i], bnd = rowp[i+1];
  for (int k=a;k<bnd;k++){
    int j = csr[k];
    const float4* p = (const float4*)&x[(size_t)j*8];
    float4 u0 = p[0], u1 = p[1];
    s[0]+=u0.x; s[1]+=u0.y; s[2]+=u0.z; s[3]+=u0.w;
    s[4]+=u1.x; s[5]+=u1.y; s[6]+=u1.z; s[7]+=u1.w;
  }
  float iv = invdeg[i];
  const float4* xp = (const float4*)&x[(size_t)i*8];
  float4 x0 = xp[0], x1 = xp[1];
  float4 o0, o1;
  o0.x = x0.x + s[0]*iv; o0.y = x0.y + s[1]*iv; o0.z = x0.z + s[2]*iv; o0.w = x0.w + s[3]*iv;
  o1.x = x1.x + s[4]*iv; o1.y = x1.y + s[5]*iv; o1.z = x1.z + s[6]*iv; o1.w = x1.w + s[7]*iv;
  ((float4*)&z8[(size_t)i*8])[0] = o0;
  ((float4*)&z8[(size_t)i*8])[1] = o1;
}

// [N x 8] @ [8 x 128] + bias, ReLU -> bf16 hi/lo pair
__global__ __launch_bounds__(256) void k_gemm8(const float* __restrict__ A, const float* __restrict__ W,
                                               const float* __restrict__ bias, unsigned short* __restrict__ Ch,
                                               unsigned short* __restrict__ Cl){
  __shared__ float Ws[8*HD];
  __shared__ float bs[HD];
  int tid = threadIdx.x;
  for (int u=tid; u<8*HD; u+=256) Ws[u] = W[u];
  if (tid < HD) bs[tid] = bias[tid];
  __syncthreads();
  int g = blockIdx.x*256 + tid;     // over NND*HD
  int row = g >> 7, c = g & 127;
  const float4* a4 = (const float4*)&A[(size_t)row*8];
  float4 a0 = a4[0], a1 = a4[1];
  float s = bs[c];
  s = fmaf(a0.x, Ws[0*128+c], s); s = fmaf(a0.y, Ws[1*128+c], s);
  s = fmaf(a0.z, Ws[2*128+c], s); s = fmaf(a0.w, Ws[3*128+c], s);
  s = fmaf(a1.x, Ws[4*128+c], s); s = fmaf(a1.y, Ws[5*128+c], s);
  s = fmaf(a1.z, Ws[6*128+c], s); s = fmaf(a1.w, Ws[7*128+c], s);
  s = fmaxf(s, 0.0f);
  unsigned short h = bf16rne(s);
  Ch[g] = h;
  Cl[g] = bf16rne(s - bf16tof(h));
}

// ---------------- MFMA GEMM: [N x 128](bf16 hi/lo) @ WT[n][k](bf16 hi/lo) + bias + ReLU ----------------
// bf16x3 error-compensated: acc += ah*wh + al*wh + ah*wl  (lo*lo dropped, ~2^-16 rel).
// 128x128 tile, 4 waves in 2x2 quadrants; per wave 4x4 frags of mfma_f32_16x16x32_bf16.
// STATS=1: fp32 out + BN column stats to part.  STATS=0: bf16 hi/lo out.
template<int STATS>
__global__ __launch_bounds__(256) void k_mgemm(const unsigned short* __restrict__ Ah, const unsigned short* __restrict__ Al,
                                               const unsigned short* __restrict__ Wh, const unsigned short* __restrict__ Wl,
                                               const float* __restrict__ bias, float* __restrict__ Cf,
                                               unsigned short* __restrict__ Ch, unsigned short* __restrict__ Cl,
                                               float* __restrict__ part){
  __shared__ unsigned short AH[128*40], AL[128*40], WH[128*40], WL[128*40];  // stride 40 bf16: 2-way banks (free)
  __shared__ float SS[256], SQ[256];
  int tid = threadIdx.x;
  int r0 = blockIdx.x * 128;
  int row = tid >> 1, half = tid & 1;
  int l = tid & 63, w = tid >> 6;
  int lane15 = l & 15, lgrp = l >> 4;
  int rw = (w >> 1) * 64, cw = (w & 1) * 64;

  f32x4 acc[4][4];
  #pragma unroll
  for (int i=0;i<4;i++)
    #pragma unroll
    for (int j=0;j<4;j++){ f32x4 z = {0.f,0.f,0.f,0.f}; acc[i][j] = z; }

  size_t abase = (size_t)(r0 + row)*HD + half*16;
  size_t wbase = (size_t)row*HD + half*16;
  float4 p0 = *(const float4*)&Ah[abase];     float4 p1 = *(const float4*)&Ah[abase+8];
  float4 p2 = *(const float4*)&Al[abase];     float4 p3 = *(const float4*)&Al[abase+8];
  float4 p4 = *(const float4*)&Wh[wbase];     float4 p5 = *(const float4*)&Wh[wbase+8];
  float4 p6 = *(const float4*)&Wl[wbase];     float4 p7 = *(const float4*)&Wl[wbase+8];

  for (int k0 = 0; k0 < 128; k0 += 32){
    __syncthreads();
    int ldst = row*40 + half*16;
    *(float4*)&AH[ldst] = p0; *(float4*)&AH[ldst+8] = p1;
    *(float4*)&AL[ldst] = p2; *(float4*)&AL[ldst+8] = p3;
    *(float4*)&WH[ldst] = p4; *(float4*)&WH[ldst+8] = p5;
    *(float4*)&WL[ldst] = p6; *(float4*)&WL[ldst+8] = p7;
    __syncthreads();
    if (k0 < 96){
      p0 = *(const float4*)&Ah[abase + k0+32]; p1 = *(const float4*)&Ah[abase + k0+40];
      p2 = *(const float4*)&Al[abase + k0+32]; p3 = *(const float4*)&Al[abase + k0+40];
      p4 = *(const float4*)&Wh[wbase + k0+32]; p5 = *(const float4*)&Wh[wbase + k0+40];
      p6 = *(const float4*)&Wl[wbase + k0+32]; p7 = *(const float4*)&Wl[wbase + k0+40];
    }
    short8 ah[4], al[4], wh[4], wl[4];
    #pragma unroll
    for (int i=0;i<4;i++){
      int ar = (rw + 16*i + lane15)*40 + lgrp*8;
      ah[i] = *(const short8*)&AH[ar];
      al[i] = *(const short8*)&AL[ar];
      int wr = (cw + 16*i + lane15)*40 + lgrp*8;
      wh[i] = *(const short8*)&WH[wr];
      wl[i] = *(const short8*)&WL[wr];
    }
    #pragma unroll
    for (int i=0;i<4;i++){
      #pragma unroll
      for (int j=0;j<4;j++){
        acc[i][j] = __builtin_amdgcn_mfma_f32_16x16x32_bf16(ah[i], wh[j], acc[i][j], 0, 0, 0);
        acc[i][j] = __builtin_amdgcn_mfma_f32_16x16x32_bf16(al[i], wh[j], acc[i][j], 0, 0, 0);
        acc[i][j] = __builtin_amdgcn_mfma_f32_16x16x32_bf16(ah[i], wl[j], acc[i][j], 0, 0, 0);
      }
    }
  }

  float bj[4], sj[4] = {0,0,0,0}, qj[4] = {0,0,0,0};
  #pragma unroll
  for (int j=0;j<4;j++) bj[j] = bias[cw + 16*j + lane15];
  #pragma unroll
  for (int i=0;i<4;i++){
    #pragma unroll
    for (int j=0;j<4;j++){
      f32x4 v = acc[i][j];
      int n = cw + 16*j + lane15;
      #pragma unroll
      for (int r=0;r<4;r++){
        float xv = fmaxf(v[r] + bj[j], 0.f);
        int m = r0 + rw + 16*i + 4*lgrp + r;
        if (STATS){
          Cf[(size_t)m*HD + n] = xv;
          sj[j] += xv;
          qj[j] = fmaf(xv, xv, qj[j]);
        } else {
          unsigned short h = bf16rne(xv);
          Ch[(size_t)m*HD + n] = h;
          Cl[(size_t)m*HD + n] = bf16rne(xv - bf16tof(h));
        }
      }
    }
  }
  if (STATS){
    #pragma unroll
    for (int j=0;j<4;j++){
      float s = sj[j], q = qj[j];
      s += __shfl_xor(s, 16); s += __shfl_xor(s, 32);
      q += __shfl_xor(q, 16); q += __shfl_xor(q, 32);
      if (lgrp == 0){
        SS[(w>>1)*128 + cw + 16*j + lane15] = s;
        SQ[(w>>1)*128 + cw + 16*j + lane15] = q;
      }
    }
    __syncthreads();
    if (tid < HD){
      part[blockIdx.x*HD + tid] = SS[tid] + SS[128 + tid];
      part[SQOFF + blockIdx.x*HD + tid] = SQ[tid] + SQ[128 + tid];
    }
  }
}

// ---------------- BN finalize: one block per feature ----------------
__global__ __launch_bounds__(256) void k_bn_fin(const float* __restrict__ part, const float* __restrict__ gamma,
                                                const float* __restrict__ beta, float* __restrict__ scale,
                                                float* __restrict__ shift){
  __shared__ float rs[256];
  __shared__ float rq[256];
  int f = blockIdx.x, t = threadIdx.x;
  rs[t] = part[t*HD + f];
  rq[t] = part[SQOFF + t*HD + f];
  __syncthreads();
  for (int d=128; d>0; d>>=1){
    if (t < d){ rs[t] += rs[t+d]; rq[t] += rq[t+d]; }
    __syncthreads();
  }
  if (t == 0){
    float mu  = rs[0] * (1.0f/NND);
    float var = rq[0] * (1.0f/NND) - mu*mu;
    float sc  = gamma[f] * rsqrtf(var + 1e-5f);
    scale[f] = sc;
    shift[f] = beta[f] - mu*sc;
  }
}

// ---------------- fused: BN-apply (folded) + mean-aggregate -> bf16 hi/lo z ----------------
__global__ __launch_bounds__(128) void k_agg_bn(const float* __restrict__ raw, const int* __restrict__ rowp,
                                                const int* __restrict__ csr, const float* __restrict__ invdeg,
                                                const float* __restrict__ scale, const float* __restrict__ shift,
                                                unsigned short* __restrict__ zh, unsigned short* __restrict__ zl){
  int i = blockIdx.x;
  int f = threadIdx.x;
  int a = rowp[i], bnd = rowp[i+1];
  float s = 0.f;
  for (int k = a; k < bnd; k++) s += raw[(size_t)csr[k]*HD + f];
  float sc = scale[f], sh = shift[f];
  size_t idx = (size_t)i*HD + f;
  float vi = fmaf(raw[idx], sc, sh);
  float zz = vi + fmaf(invdeg[i]*sc, s, (bnd > a) ? sh : 0.f);
  unsigned short h = bf16rne(zz);
  zh[idx] = h;
  zl[idx] = bf16rne(zz - bf16tof(h));
}

// ---------------- gpool from per-block part colsums ----------------
__global__ __launch_bounds__(128) void k_gpool(const float* __restrict__ part, const float* __restrict__ bnsc,
                                               const float* __restrict__ bnsh, float* __restrict__ gsum){
  int b = blockIdx.x, f = threadIdx.x;
  float g = 0.f;
  #pragma unroll
  for (int l=0;l<4;l++){
    float s = 0.f;
    #pragma unroll
    for (int t=0;t<8;t++) s += part[l*PSLOT + (b*8 + t)*HD + f];
    g += fmaf(bnsc[l*128+f], s, 1024.0f*bnsh[l*128+f]);
  }
  gsum[b*HD + f] = g;
}

// ---------------- build aug rows (npool on the fly from raw0..raw3) ----------------
__global__ __launch_bounds__(256) void k_build_aug(const int* __restrict__ mrows, const int* __restrict__ mcols,
                                                   const float* __restrict__ raw0, const float* __restrict__ raw1,
                                                   const float* __restrict__ raw2, const float* __restrict__ raw3,
                                                   const float* __restrict__ bnsc, const float* __restrict__ bnsh,
                                                   const float* __restrict__ gsum, float* __restrict__ aug){
  int idx = blockIdx.x;     // 0..4095: first 2048 = row nodes, next 2048 = col nodes
  int t = threadIdx.x;
  int j = idx & 2047;
  int rg = mrows[j];
  int b = rg >> 10;
  int g = (idx >= 2048) ? ((b << 10) | mcols[j]) : rg;
  float v;
  if (t < 128){
    size_t o = (size_t)g*HD + t;
    v = fmaf(bnsc[t],     raw0[o], bnsh[t]);
    v = fmaf(bnsc[128+t], raw1[o], v + bnsh[128+t]);
    v = fmaf(bnsc[256+t], raw2[o], v + bnsh[256+t]);
    v = fmaf(bnsc[384+t], raw3[o], v + bnsh[384+t]);
  } else {
    v = gsum[b*HD + (t-128)] * (1.0f/1024.0f);
  }
  aug[(size_t)idx*256 + t] = v;
}

// fused policy layer: C = tanh(A@W1+b1)@W2+b2.  64-row tile (proven).
template<int K1>
__global__ __launch_bounds__(256) void k_pol(const float* __restrict__ A, const float* __restrict__ W1,
                                             const float* __restrict__ b1, const float* __restrict__ W2,
                                             const float* __restrict__ b2, float* __restrict__ C){
  __shared__ float S1[32*128 + 64*36];
  __shared__ float T[64*132];
  int tid = threadIdx.x;
  int r0 = blockIdx.x * 64;
  int tc = tid & 15, rg = tid >> 4;
  int c0 = tc * 4;
  float4 acc0[4], acc1[4];
  #pragma unroll
  for (int j=0;j<4;j++){ acc0[j] = make_float4(0,0,0,0); acc1[j] = make_float4(0,0,0,0); }
  for (int k0 = 0; k0 < K1; k0 += 32){
    __syncthreads();
    #pragma unroll
    for (int u=0;u<4;u++){
      int e = tid + u*256;
      *(float4*)&S1[(e>>5)*HD + ((e&31)<<2)] = *(const float4*)&W1[(size_t)(k0 + (e>>5))*HD + ((e&31)<<2)];
    }
    #pragma unroll
    for (int u=0;u<2;u++){
      int e = tid + u*256;
      *(float4*)&S1[4096 + (e>>3)*36 + ((e&7)<<2)] = *(const float4*)&A[(size_t)(r0 + (e>>3))*K1 + k0 + ((e&7)<<2)];
    }
    __syncthreads();
    #pragma unroll
    for (int kk=0; kk<32; kk+=4){
      float4 w0[4], w1[4];
      #pragma unroll
      for (int q=0;q<4;q++){
        w0[q] = *(const float4*)&S1[(kk+q)*HD + c0];
        w1[q] = *(const float4*)&S1[(kk+q)*HD + c0 + 64];
      }
      #pragma unroll
      for (int j=0;j<4;j++){
        float4 av = *(const float4*)&S1[4096 + (rg+16*j)*36 + kk];
        fma4(acc0[j], av.x, w0[0]); fma4(acc1[j], av.x, w1[0]);
        fma4(acc0[j], av.y, w0[1]); fma4(acc1[j], av.y, w1[1]);
        fma4(acc0[j], av.z, w0[2]); fma4(acc1[j], av.z, w1[2]);
        fma4(acc0[j], av.w, w0[3]); fma4(acc1[j], av.w, w1[3]);
      }
    }
  }
  {
    float4 bA = *(const float4*)&b1[c0];
    float4 bB = *(const float4*)&b1[c0+64];
    #pragma unroll
    for (int j=0;j<4;j++){
      int r = rg + 16*j;
      float4 v0 = acc0[j], v1 = acc1[j];
      v0.x = tanhf(v0.x + bA.x); v0.y = tanhf(v0.y + bA.y);
      v0.z = tanhf(v0.z + bA.z); v0.w = tanhf(v0.w + bA.w);
      v1.x = tanhf(v1.x + bB.x); v1.y = tanhf(v1.y + bB.y);
      v1.z = tanhf(v1.z + bB.z); v1.w = tanhf(v1.w + bB.w);
      *(float4*)&T[r*132 + c0] = v0;
      *(float4*)&T[r*132 + c0 + 64] = v1;
    }
  }
  float4 d0[4], d1[4];
  #pragma unroll
  for (int j=0;j<4;j++){ d0[j] = make_float4(0,0,0,0); d1[j] = make_float4(0,0,0,0); }
  for (int k0 = 0; k0 < HD; k0 += 32){
    __syncthreads();
    #pragma unroll
    for (int u=0;u<4;u++){
      int e = tid + u*256;
      *(float4*)&S1[(e>>5)*HD + ((e&31)<<2)] = *(const float4*)&W2[(size_t)(k0 + (e>>5))*HD + ((e&31)<<2)];
    }
    __syncthreads();
    #pragma unroll
    for (int kk=0; kk<32; kk+=4){
      float4 w0[4], w1[4];
      #pragma unroll
      for (int q=0;q<4;q++){
        w0[q] = *(const float4*)&S1[(kk+q)*HD + c0];
        w1[q] = *(const float4*)&S1[(kk+q)*HD + c0 + 64];
      }
      #pragma unroll
      for (int j=0;j<4;j++){
        float4 av = *(const float4*)&T[(rg+16*j)*132 + k0 + kk];
        fma4(d0[j], av.x, w0[0]); fma4(d1[j], av.x, w1[0]);
        fma4(d0[j], av.y, w0[1]); fma4(d1[j], av.y, w1[1]);
        fma4(d0[j], av.z, w0[2]); fma4(d1[j], av.z, w1[2]);
        fma4(d0[j], av.w, w0[3]); fma4(d1[j], av.w, w1[3]);
      }
    }
  }
  float4 bA = *(const float4*)&b2[c0];
  float4 bB = *(const float4*)&b2[c0+64];
  #pragma unroll
  for (int j=0;j<4;j++){
    int row = r0 + rg + 16*j;
    float4 v0 = d0[j], v1 = d1[j];
    v0.x += bA.x; v0.y += bA.y; v0.z += bA.z; v0.w += bA.w;
    v1.x += bB.x; v1.y += bB.y; v1.z += bB.z; v1.w += bB.w;
    *(float4*)&C[(size_t)row*HD + c0] = v0;
    *(float4*)&C[(size_t)row*HD + c0 + 64] = v1;
  }
}

// score + per-batch sparse softmax (dedup of repeated cells) + scatter
__global__ __launch_bounds__(64) void k_score(const float* __restrict__ Z, const int* __restrict__ mrows,
                                              const int* __restrict__ mcols, float* __restrict__ out){
  __shared__ int rr[64]; __shared__ int cc[64]; __shared__ float red[64];
  int b = blockIdx.x, f = threadIdx.x;
  int i = b*64 + f;
  int rg = mrows[i];
  int row = rg & 1023;
  int col = mcols[i];
  const float4* zr = (const float4*)&Z[(size_t)i*HD];
  const float4* zc = (const float4*)&Z[(size_t)(NPAIR + i)*HD];
  float s = 0.f;
  #pragma unroll
  for (int k=0;k<32;k++){
    float4 a = zr[k], c = zc[k];
    s = fmaf(a.x,c.x, fmaf(a.y,c.y, fmaf(a.z,c.z, fmaf(a.w,c.w, s))));
  }
  rr[f]=row; cc[f]=col; red[f]=s;
  __syncthreads();
  for (int d=32; d>0; d>>=1){
    if (f<d) red[f] = fmaxf(red[f], red[f+d]);
    __syncthreads();
  }
  float m = red[0];
  __syncthreads();
  bool first = true;
  for (int j=0;j<f;j++) if (rr[j]==row && cc[j]==col) first = false;
  float e = expf(s - m);
  red[f] = first ? e : 0.0f;
  __syncthreads();
  for (int d=32; d>0; d>>=1){
    if (f<d) red[f] += red[f+d];
    __syncthreads();
  }
  float denom = red[0];
  out[(size_t)b*1048576 + row*1024 + col] = e / denom;
}

extern "C" void kernel_launch(void* const* d_in, const int* in_sizes, int n_in,
                              void* d_out, int out_size, void* d_ws, size_t ws_size,
                              hipStream_t stream){
  const float* x     = (const float*)d_in[0];
  const int*   ei    = (const int*)d_in[1];
  const int*   mrows = (const int*)d_in[3];
  const int*   mcols = (const int*)d_in[4];
  const float* g0w1  = (const float*)d_in[5];
  const float* g0b1  = (const float*)d_in[6];
  const float* g0w2  = (const float*)d_in[7];
  const float* g0b2  = (const float*)d_in[8];
  const float* gw1   = (const float*)d_in[9];
  const float* gb1   = (const float*)d_in[10];
  const float* gw2   = (const float*)d_in[11];
  const float* gb2   = (const float*)d_in[12];
  const float* bng   = (const float*)d_in[13];
  const float* bnb   = (const float*)d_in[14];
  const float* p0w1  = (const float*)d_in[15];
  const float* p0b1  = (const float*)d_in[16];
  const float* p0w2  = (const float*)d_in[17];
  const float* p0b2  = (const float*)d_in[18];
  const float* pw1   = (const float*)d_in[19];
  const float* pb1   = (const float*)d_in[20];
  const float* pw2   = (const float*)d_in[21];
  const float* pb2   = (const float*)d_in[22];

  float* fw    = (float*)d_ws;
  float* raw0  = fw;                        // N*H
  float* raw1  = fw + 4194304;
  float* raw2  = fw + 8388608;
  float* raw3  = fw + 12582912;
  float* aug   = fw + 16777216;             // 4096*256
  float* pX    = fw + 17825792;             // 4096*128
  float* pY    = fw + 18350080;
  float* pZ    = fw + 18874368;
  float* z8    = fw + 19398656;             // N*8
  float* invdeg= fw + 19660800;             // N
  float* bnsc  = fw + 19693568;             // 4*128
  float* bnsh  = fw + 19694080;
  float* part  = fw + 19694592;             // 4*PSLOT
  float* gsum  = fw + 19956736;             // B*H
  int*   cnt   = (int*)(fw + 19960832);     // N
  int*   fillc = cnt + NND;                 // N
  int*   rowp  = fillc + NND;               // N+1
  int*   csr   = rowp + NND + 1;            // E
  unsigned short* us = (unsigned short*)(fw + 20500000);
  unsigned short* zHi  = us;                // N*H bf16
  unsigned short* zLo  = us + 4194304;
  unsigned short* tHi  = us + 8388608;
  unsigned short* tLo  = us + 12582912;
  unsigned short* WThi = us + 16777216;     // 7*128*128
  unsigned short* WTlo = us + 16891904;
  float* raws[4] = {raw0, raw1, raw2, raw3};

  const int* src = ei;
  const int* dst = ei + NE;

  hipLaunchKernelGGL(k_zero, dim3(2048), dim3(256), 0, stream, (float4*)d_out, out_size/4);
  hipMemsetAsync(cnt, 0, (size_t)(2*NND)*4, stream);   // cnt, fillc
  hipLaunchKernelGGL(k_wsplit, dim3(8,7), dim3(256), 0, stream, g0w2, gw1, gw2, WThi, WTlo);

  hipLaunchKernelGGL(k_count, dim3(NE/256), dim3(256), 0, stream, dst, cnt);
  hipLaunchKernelGGL(k_scan, dim3(1), dim3(1024), 0, stream, cnt, rowp, invdeg);
  hipLaunchKernelGGL(k_fill, dim3(NE/256), dim3(256), 0, stream, src, dst, rowp, fillc, csr);

  // layer 0
  hipLaunchKernelGGL(k_agg8, dim3(NND/256), dim3(256), 0, stream, x, rowp, csr, invdeg, z8);
  hipLaunchKernelGGL(k_gemm8, dim3(NND*HD/256), dim3(256), 0, stream, z8, g0w1, g0b1, tHi, tLo);
  hipLaunchKernelGGL((k_mgemm<1>), dim3(NBLK), dim3(256), 0, stream, tHi, tLo, WThi, WTlo, g0b2,
                     raw0, (unsigned short*)nullptr, (unsigned short*)nullptr, part);
  hipLaunchKernelGGL(k_bn_fin, dim3(128), dim3(256), 0, stream, part, bng, bnb, bnsc, bnsh);

  // layers 1..3
  for (int l=0;l<3;l++){
    hipLaunchKernelGGL(k_agg_bn, dim3(NND), dim3(128), 0, stream, raws[l], rowp, csr, invdeg,
                       bnsc + l*128, bnsh + l*128, zHi, zLo);
    hipLaunchKernelGGL((k_mgemm<0>), dim3(NBLK), dim3(256), 0, stream, zHi, zLo,
                       WThi + (1+l)*16384, WTlo + (1+l)*16384, gb1 + l*128,
                       (float*)nullptr, tHi, tLo, (float*)nullptr);
    hipLaunchKernelGGL((k_mgemm<1>), dim3(NBLK), dim3(256), 0, stream, tHi, tLo,
                       WThi + (4+l)*16384, WTlo + (4+l)*16384, gb2 + l*128,
                       raws[l+1], (unsigned short*)nullptr, (unsigned short*)nullptr, part + (l+1)*PSLOT);
    hipLaunchKernelGGL(k_bn_fin, dim3(128), dim3(256), 0, stream, part + (l+1)*PSLOT, bng + (l+1)*128, bnb + (l+1)*128,
                       bnsc + (l+1)*128, bnsh + (l+1)*128);
  }

  // gpool from part colsums; npool on the fly in build_aug
  hipLaunchKernelGGL(k_gpool, dim3(32), dim3(128), 0, stream, part, bnsc, bnsh, gsum);
  hipLaunchKernelGGL(k_build_aug, dim3(4096), dim3(256), 0, stream, mrows, mcols,
                     raw0, raw1, raw2, raw3, bnsc, bnsh, gsum, aug);

  hipLaunchKernelGGL((k_pol<256>), dim3(64), dim3(256), 0, stream, aug, p0w1, p0b1, p0w2, p0b2, pX);
  hipLaunchKernelGGL((k_pol<128>), dim3(64), dim3(256), 0, stream, pX, pw1, pb1, pw2, pb2, pY);
  hipLaunchKernelGGL((k_pol<128>), dim3(64), dim3(256), 0, stream, pY, pw1 + 16384, pb1 + 128, pw2 + 16384, pb2 + 128, pZ);

  hipLaunchKernelGGL(k_score, dim3(32), dim3(64), 0, stream, pZ, mrows, mcols, (float*)d_out);
}

// Round 9
// 407.716 us; speedup vs baseline: 1.5337x; 1.0013x over previous
//
#include <hip/hip_runtime.h>

#define NND 32768      // total nodes N = B*NNODES
#define NE  262144     // edges
#define HD 128
#define NPAIR 2048     // B*FEAS
#define NBLK 256       // mgemm blocks (NND/128)
#define SQOFF 32768    // NBLK*128, sqsum offset within a part slot
#define PSLOT 65536    // 2*NBLK*128, per-layer part slot

typedef __attribute__((ext_vector_type(8))) short short8;
typedef __attribute__((ext_vector_type(4))) float f32x4;

__device__ __forceinline__ void fma4(float4& a, float s, const float4& w){
  a.x = fmaf(s, w.x, a.x);
  a.y = fmaf(s, w.y, a.y);
  a.z = fmaf(s, w.z, a.z);
  a.w = fmaf(s, w.w, a.w);
}

__device__ __forceinline__ unsigned short bf16rne(float x){
  unsigned int u = __float_as_uint(x);
  unsigned int r = u + 0x7FFFu + ((u >> 16) & 1u);
  return (unsigned short)(r >> 16);
}
__device__ __forceinline__ float bf16tof(unsigned short h){
  return __uint_as_float(((unsigned int)h) << 16);
}

// ---------------- output zero-fill ----------------
__global__ __launch_bounds__(256) void k_zero(float4* __restrict__ p, int n4){
  int i = blockIdx.x*256 + threadIdx.x;
  int stride = gridDim.x*256;
  float4 z = make_float4(0.f,0.f,0.f,0.f);
  for (; i < n4; i += stride) p[i] = z;
}

// ---------------- weight split+transpose: W[k][n] fp32 -> WT{hi,lo}[n][k] bf16 ----------------
__global__ __launch_bounds__(256) void k_wsplit(const float* __restrict__ g0w2, const float* __restrict__ gw1,
                                                const float* __restrict__ gw2, unsigned short* __restrict__ WThi,
                                                unsigned short* __restrict__ WTlo){
  __shared__ float tile[16*129];
  int kblk = blockIdx.x, mat = blockIdx.y;
  int k0 = kblk * 16;
  const float* W = (mat == 0) ? g0w2 : ((mat < 4) ? (gw1 + (mat-1)*16384) : (gw2 + (mat-4)*16384));
  int t = threadIdx.x;
  {
    int kk = t >> 4, n0 = (t & 15) * 8;
    float4 v0 = *(const float4*)&W[(size_t)(k0+kk)*HD + n0];
    float4 v1 = *(const float4*)&W[(size_t)(k0+kk)*HD + n0 + 4];
    tile[kk*129 + n0+0] = v0.x; tile[kk*129 + n0+1] = v0.y;
    tile[kk*129 + n0+2] = v0.z; tile[kk*129 + n0+3] = v0.w;
    tile[kk*129 + n0+4] = v1.x; tile[kk*129 + n0+5] = v1.y;
    tile[kk*129 + n0+6] = v1.z; tile[kk*129 + n0+7] = v1.w;
  }
  __syncthreads();
  int n = t >> 1, koff = (t & 1) * 8;
  short8 hv, lv;
  #pragma unroll
  for (int q=0;q<8;q++){
    float v = tile[(koff+q)*129 + n];
    unsigned short h = bf16rne(v);
    hv[q] = (short)h;
    lv[q] = (short)bf16rne(v - bf16tof(h));
  }
  size_t o = (size_t)mat*16384 + (size_t)n*HD + k0 + koff;
  *(short8*)&WThi[o] = hv;
  *(short8*)&WTlo[o] = lv;
}

// ---------------- CSR build ----------------
__global__ __launch_bounds__(256) void k_count(const int* __restrict__ dst, int* __restrict__ cnt){
  int e = blockIdx.x*256 + threadIdx.x;
  if (e < NE) atomicAdd(&cnt[dst[e]], 1);
}

__global__ __launch_bounds__(1024) void k_scan(const int* __restrict__ cnt, int* __restrict__ rowp,
                                               float* __restrict__ invdeg){
  __shared__ int part[1024];
  int t = threadIdx.x;
  int base = t*32;
  int local[32];
  int s = 0;
  #pragma unroll
  for (int j=0;j<32;j++){ local[j] = s; s += cnt[base+j]; }
  part[t] = s;
  __syncthreads();
  for (int d=1; d<1024; d<<=1){
    int v = (t>=d) ? part[t-d] : 0;
    __syncthreads();
    part[t] += v;
    __syncthreads();
  }
  int off = (t==0) ? 0 : part[t-1];
  #pragma unroll
  for (int j=0;j<32;j++){
    rowp[base+j] = off + local[j];
    int c = cnt[base+j];
    invdeg[base+j] = 1.0f / (float)(c > 0 ? c : 1);
  }
  if (t == 1023) rowp[NND] = off + s;
}

__global__ __launch_bounds__(256) void k_fill(const int* __restrict__ src, const int* __restrict__ dst,
                                              const int* __restrict__ rowp, int* __restrict__ fillc,
                                              int* __restrict__ csr){
  int e = blockIdx.x*256 + threadIdx.x;
  if (e < NE){
    int d = dst[e];
    int p = atomicAdd(&fillc[d], 1);
    csr[rowp[d] + p] = src[e];
  }
}

// ---------------- layer-0 aggregation (IN=8) ----------------
__global__ __launch_bounds__(256) void k_agg8(const float* __restrict__ x, const int* __restrict__ rowp,
                                              const int* __restrict__ csr, const float* __restrict__ invdeg,
                                              float* __restrict__ z8){
  int i = blockIdx.x*256 + threadIdx.x;
  float s[8] = {0,0,0,0,0,0,0,0};
  int a = rowp[i], bnd = rowp[i+1];
  for (int k=a;k<bnd;k++){
    int j = csr[k];
    const float4* p = (const float4*)&x[(size_t)j*8];
    float4 u0 = p[0], u1 = p[1];
    s[0]+=u0.x; s[1]+=u0.y; s[2]+=u0.z; s[3]+=u0.w;
    s[4]+=u1.x; s[5]+=u1.y; s[6]+=u1.z; s[7]+=u1.w;
  }
  float iv = invdeg[i];
  const float4* xp = (const float4*)&x[(size_t)i*8];
  float4 x0 = xp[0], x1 = xp[1];
  float4 o0, o1;
  o0.x = x0.x + s[0]*iv; o0.y = x0.y + s[1]*iv; o0.z = x0.z + s[2]*iv; o0.w = x0.w + s[3]*iv;
  o1.x = x1.x + s[4]*iv; o1.y = x1.y + s[5]*iv; o1.z = x1.z + s[6]*iv; o1.w = x1.w + s[7]*iv;
  ((float4*)&z8[(size_t)i*8])[0] = o0;
  ((float4*)&z8[(size_t)i*8])[1] = o1;
}

// [N x 8] @ [8 x 128] + bias, ReLU -> bf16 hi/lo pair
__global__ __launch_bounds__(256) void k_gemm8(const float* __restrict__ A, const float* __restrict__ W,
                                               const float* __restrict__ bias, unsigned short* __restrict__ Ch,
                                               unsigned short* __restrict__ Cl){
  __shared__ float Ws[8*HD];
  __shared__ float bs[HD];
  int tid = threadIdx.x;
  for (int u=tid; u<8*HD; u+=256) Ws[u] = W[u];
  if (tid < HD) bs[tid] = bias[tid];
  __syncthreads();
  int g = blockIdx.x*256 + tid;     // over NND*HD
  int row = g >> 7, c = g & 127;
  const float4* a4 = (const float4*)&A[(size_t)row*8];
  float4 a0 = a4[0], a1 = a4[1];
  float s = bs[c];
  s = fmaf(a0.x, Ws[0*128+c], s); s = fmaf(a0.y, Ws[1*128+c], s);
  s = fmaf(a0.z, Ws[2*128+c], s); s = fmaf(a0.w, Ws[3*128+c], s);
  s = fmaf(a1.x, Ws[4*128+c], s); s = fmaf(a1.y, Ws[5*128+c], s);
  s = fmaf(a1.z, Ws[6*128+c], s); s = fmaf(a1.w, Ws[7*128+c], s);
  s = fmaxf(s, 0.0f);
  unsigned short h = bf16rne(s);
  Ch[g] = h;
  Cl[g] = bf16rne(s - bf16tof(h));
}

// ---------------- MFMA GEMM: [N x 128](bf16 hi/lo) @ WT[n][k](bf16 hi/lo) + bias + ReLU ----------------
// bf16x3 error-compensated: acc += ah*wh + al*wh + ah*wl  (lo*lo dropped, ~2^-16 rel).
// 128x128 tile, 4 waves in 2x2 quadrants; per wave 4x4 frags of mfma_f32_16x16x32_bf16.
// STATS=1: fp32 out + BN column stats to part.  STATS=0: bf16 hi/lo out.
template<int STATS>
__global__ __launch_bounds__(256) void k_mgemm(const unsigned short* __restrict__ Ah, const unsigned short* __restrict__ Al,
                                               const unsigned short* __restrict__ Wh, const unsigned short* __restrict__ Wl,
                                               const float* __restrict__ bias, float* __restrict__ Cf,
                                               unsigned short* __restrict__ Ch, unsigned short* __restrict__ Cl,
                                               float* __restrict__ part){
  __shared__ unsigned short AH[128*40], AL[128*40], WH[128*40], WL[128*40];  // stride 40 bf16: 2-way banks (free)
  __shared__ float SS[256], SQ[256];
  int tid = threadIdx.x;
  int r0 = blockIdx.x * 128;
  int row = tid >> 1, half = tid & 1;
  int l = tid & 63, w = tid >> 6;
  int lane15 = l & 15, lgrp = l >> 4;
  int rw = (w >> 1) * 64, cw = (w & 1) * 64;

  f32x4 acc[4][4];
  #pragma unroll
  for (int i=0;i<4;i++)
    #pragma unroll
    for (int j=0;j<4;j++){ f32x4 z = {0.f,0.f,0.f,0.f}; acc[i][j] = z; }

  size_t abase = (size_t)(r0 + row)*HD + half*16;
  size_t wbase = (size_t)row*HD + half*16;
  float4 p0 = *(const float4*)&Ah[abase];     float4 p1 = *(const float4*)&Ah[abase+8];
  float4 p2 = *(const float4*)&Al[abase];     float4 p3 = *(const float4*)&Al[abase+8];
  float4 p4 = *(const float4*)&Wh[wbase];     float4 p5 = *(const float4*)&Wh[wbase+8];
  float4 p6 = *(const float4*)&Wl[wbase];     float4 p7 = *(const float4*)&Wl[wbase+8];

  for (int k0 = 0; k0 < 128; k0 += 32){
    __syncthreads();
    int ldst = row*40 + half*16;
    *(float4*)&AH[ldst] = p0; *(float4*)&AH[ldst+8] = p1;
    *(float4*)&AL[ldst] = p2; *(float4*)&AL[ldst+8] = p3;
    *(float4*)&WH[ldst] = p4; *(float4*)&WH[ldst+8] = p5;
    *(float4*)&WL[ldst] = p6; *(float4*)&WL[ldst+8] = p7;
    __syncthreads();
    if (k0 < 96){
      p0 = *(const float4*)&Ah[abase + k0+32]; p1 = *(const float4*)&Ah[abase + k0+40];
      p2 = *(const float4*)&Al[abase + k0+32]; p3 = *(const float4*)&Al[abase + k0+40];
      p4 = *(const float4*)&Wh[wbase + k0+32]; p5 = *(const float4*)&Wh[wbase + k0+40];
      p6 = *(const float4*)&Wl[wbase + k0+32]; p7 = *(const float4*)&Wl[wbase + k0+40];
    }
    short8 ah[4], al[4], wh[4], wl[4];
    #pragma unroll
    for (int i=0;i<4;i++){
      int ar = (rw + 16*i + lane15)*40 + lgrp*8;
      ah[i] = *(const short8*)&AH[ar];
      al[i] = *(const short8*)&AL[ar];
      int wr = (cw + 16*i + lane15)*40 + lgrp*8;
      wh[i] = *(const short8*)&WH[wr];
      wl[i] = *(const short8*)&WL[wr];
    }
    #pragma unroll
    for (int i=0;i<4;i++){
      #pragma unroll
      for (int j=0;j<4;j++){
        acc[i][j] = __builtin_amdgcn_mfma_f32_16x16x32_bf16(ah[i], wh[j], acc[i][j], 0, 0, 0);
        acc[i][j] = __builtin_amdgcn_mfma_f32_16x16x32_bf16(al[i], wh[j], acc[i][j], 0, 0, 0);
        acc[i][j] = __builtin_amdgcn_mfma_f32_16x16x32_bf16(ah[i], wl[j], acc[i][j], 0, 0, 0);
      }
    }
  }

  float bj[4], sj[4] = {0,0,0,0}, qj[4] = {0,0,0,0};
  #pragma unroll
  for (int j=0;j<4;j++) bj[j] = bias[cw + 16*j + lane15];
  #pragma unroll
  for (int i=0;i<4;i++){
    #pragma unroll
    for (int j=0;j<4;j++){
      f32x4 v = acc[i][j];
      int n = cw + 16*j + lane15;
      #pragma unroll
      for (int r=0;r<4;r++){
        float xv = fmaxf(v[r] + bj[j], 0.f);
        int m = r0 + rw + 16*i + 4*lgrp + r;
        if (STATS){
          Cf[(size_t)m*HD + n] = xv;
          sj[j] += xv;
          qj[j] = fmaf(xv, xv, qj[j]);
        } else {
          unsigned short h = bf16rne(xv);
          Ch[(size_t)m*HD + n] = h;
          Cl[(size_t)m*HD + n] = bf16rne(xv - bf16tof(h));
        }
      }
    }
  }
  if (STATS){
    #pragma unroll
    for (int j=0;j<4;j++){
      float s = sj[j], q = qj[j];
      s += __shfl_xor(s, 16); s += __shfl_xor(s, 32);
      q += __shfl_xor(q, 16); q += __shfl_xor(q, 32);
      if (lgrp == 0){
        SS[(w>>1)*128 + cw + 16*j + lane15] = s;
        SQ[(w>>1)*128 + cw + 16*j + lane15] = q;
      }
    }
    __syncthreads();
    if (tid < HD){
      part[blockIdx.x*HD + tid] = SS[tid] + SS[128 + tid];
      part[SQOFF + blockIdx.x*HD + tid] = SQ[tid] + SQ[128 + tid];
    }
  }
}

// ---------------- BN finalize: one block per feature ----------------
__global__ __launch_bounds__(256) void k_bn_fin(const float* __restrict__ part, const float* __restrict__ gamma,
                                                const float* __restrict__ beta, float* __restrict__ scale,
                                                float* __restrict__ shift){
  __shared__ float rs[256];
  __shared__ float rq[256];
  int f = blockIdx.x, t = threadIdx.x;
  rs[t] = part[t*HD + f];
  rq[t] = part[SQOFF + t*HD + f];
  __syncthreads();
  for (int d=128; d>0; d>>=1){
    if (t < d){ rs[t] += rs[t+d]; rq[t] += rq[t+d]; }
    __syncthreads();
  }
  if (t == 0){
    float mu  = rs[0] * (1.0f/NND);
    float var = rq[0] * (1.0f/NND) - mu*mu;
    float sc  = gamma[f] * rsqrtf(var + 1e-5f);
    scale[f] = sc;
    shift[f] = beta[f] - mu*sc;
  }
}

// ---------------- fused: BN-apply (folded) + mean-aggregate -> bf16 hi/lo z ----------------
__global__ __launch_bounds__(128) void k_agg_bn(const float* __restrict__ raw, const int* __restrict__ rowp,
                                                const int* __restrict__ csr, const float* __restrict__ invdeg,
                                                const float* __restrict__ scale, const float* __restrict__ shift,
                                                unsigned short* __restrict__ zh, unsigned short* __restrict__ zl){
  int i = blockIdx.x;
  int f = threadIdx.x;
  int a = rowp[i], bnd = rowp[i+1];
  float s = 0.f;
  for (int k = a; k < bnd; k++) s += raw[(size_t)csr[k]*HD + f];
  float sc = scale[f], sh = shift[f];
  size_t idx = (size_t)i*HD + f;
  float vi = fmaf(raw[idx], sc, sh);
  float zz = vi + fmaf(invdeg[i]*sc, s, (bnd > a) ? sh : 0.f);
  unsigned short h = bf16rne(zz);
  zh[idx] = h;
  zl[idx] = bf16rne(zz - bf16tof(h));
}

// ---------------- gpool from per-block part colsums ----------------
__global__ __launch_bounds__(128) void k_gpool(const float* __restrict__ part, const float* __restrict__ bnsc,
                                               const float* __restrict__ bnsh, float* __restrict__ gsum){
  int b = blockIdx.x, f = threadIdx.x;
  float g = 0.f;
  #pragma unroll
  for (int l=0;l<4;l++){
    float s = 0.f;
    #pragma unroll
    for (int t=0;t<8;t++) s += part[l*PSLOT + (b*8 + t)*HD + f];
    g += fmaf(bnsc[l*128+f], s, 1024.0f*bnsh[l*128+f]);
  }
  gsum[b*HD + f] = g;
}

// ---------------- build aug rows (npool on the fly from raw0..raw3) ----------------
__global__ __launch_bounds__(256) void k_build_aug(const int* __restrict__ mrows, const int* __restrict__ mcols,
                                                   const float* __restrict__ raw0, const float* __restrict__ raw1,
                                                   const float* __restrict__ raw2, const float* __restrict__ raw3,
                                                   const float* __restrict__ bnsc, const float* __restrict__ bnsh,
                                                   const float* __restrict__ gsum, float* __restrict__ aug){
  int idx = blockIdx.x;     // 0..4095: first 2048 = row nodes, next 2048 = col nodes
  int t = threadIdx.x;
  int j = idx & 2047;
  int rg = mrows[j];
  int b = rg >> 10;
  int g = (idx >= 2048) ? ((b << 10) | mcols[j]) : rg;
  float v;
  if (t < 128){
    size_t o = (size_t)g*HD + t;
    v = fmaf(bnsc[t],     raw0[o], bnsh[t]);
    v = fmaf(bnsc[128+t], raw1[o], v + bnsh[128+t]);
    v = fmaf(bnsc[256+t], raw2[o], v + bnsh[256+t]);
    v = fmaf(bnsc[384+t], raw3[o], v + bnsh[384+t]);
  } else {
    v = gsum[b*HD + (t-128)] * (1.0f/1024.0f);
  }
  aug[(size_t)idx*256 + t] = v;
}

// fused policy layer: C = tanh(A@W1+b1)@W2+b2.  64-row tile (proven).
template<int K1>
__global__ __launch_bounds__(256) void k_pol(const float* __restrict__ A, const float* __restrict__ W1,
                                             const float* __restrict__ b1, const float* __restrict__ W2,
                                             const float* __restrict__ b2, float* __restrict__ C){
  __shared__ float S1[32*128 + 64*36];
  __shared__ float T[64*132];
  int tid = threadIdx.x;
  int r0 = blockIdx.x * 64;
  int tc = tid & 15, rg = tid >> 4;
  int c0 = tc * 4;
  float4 acc0[4], acc1[4];
  #pragma unroll
  for (int j=0;j<4;j++){ acc0[j] = make_float4(0,0,0,0); acc1[j] = make_float4(0,0,0,0); }
  for (int k0 = 0; k0 < K1; k0 += 32){
    __syncthreads();
    #pragma unroll
    for (int u=0;u<4;u++){
      int e = tid + u*256;
      *(float4*)&S1[(e>>5)*HD + ((e&31)<<2)] = *(const float4*)&W1[(size_t)(k0 + (e>>5))*HD + ((e&31)<<2)];
    }
    #pragma unroll
    for (int u=0;u<2;u++){
      int e = tid + u*256;
      *(float4*)&S1[4096 + (e>>3)*36 + ((e&7)<<2)] = *(const float4*)&A[(size_t)(r0 + (e>>3))*K1 + k0 + ((e&7)<<2)];
    }
    __syncthreads();
    #pragma unroll
    for (int kk=0; kk<32; kk+=4){
      float4 w0[4], w1[4];
      #pragma unroll
      for (int q=0;q<4;q++){
        w0[q] = *(const float4*)&S1[(kk+q)*HD + c0];
        w1[q] = *(const float4*)&S1[(kk+q)*HD + c0 + 64];
      }
      #pragma unroll
      for (int j=0;j<4;j++){
        float4 av = *(const float4*)&S1[4096 + (rg+16*j)*36 + kk];
        fma4(acc0[j], av.x, w0[0]); fma4(acc1[j], av.x, w1[0]);
        fma4(acc0[j], av.y, w0[1]); fma4(acc1[j], av.y, w1[1]);
        fma4(acc0[j], av.z, w0[2]); fma4(acc1[j], av.z, w1[2]);
        fma4(acc0[j], av.w, w0[3]); fma4(acc1[j], av.w, w1[3]);
      }
    }
  }
  {
    float4 bA = *(const float4*)&b1[c0];
    float4 bB = *(const float4*)&b1[c0+64];
    #pragma unroll
    for (int j=0;j<4;j++){
      int r = rg + 16*j;
      float4 v0 = acc0[j], v1 = acc1[j];
      v0.x = tanhf(v0.x + bA.x); v0.y = tanhf(v0.y + bA.y);
      v0.z = tanhf(v0.z + bA.z); v0.w = tanhf(v0.w + bA.w);
      v1.x = tanhf(v1.x + bB.x); v1.y = tanhf(v1.y + bB.y);
      v1.z = tanhf(v1.z + bB.z); v1.w = tanhf(v1.w + bB.w);
      *(float4*)&T[r*132 + c0] = v0;
      *(float4*)&T[r*132 + c0 + 64] = v1;
    }
  }
  float4 d0[4], d1[4];
  #pragma unroll
  for (int j=0;j<4;j++){ d0[j] = make_float4(0,0,0,0); d1[j] = make_float4(0,0,0,0); }
  for (int k0 = 0; k0 < HD; k0 += 32){
    __syncthreads();
    #pragma unroll
    for (int u=0;u<4;u++){
      int e = tid + u*256;
      *(float4*)&S1[(e>>5)*HD + ((e&31)<<2)] = *(const float4*)&W2[(size_t)(k0 + (e>>5))*HD + ((e&31)<<2)];
    }
    __syncthreads();
    #pragma unroll
    for (int kk=0; kk<32; kk+=4){
      float4 w0[4], w1[4];
      #pragma unroll
      for (int q=0;q<4;q++){
        w0[q] = *(const float4*)&S1[(kk+q)*HD + c0];
        w1[q] = *(const float4*)&S1[(kk+q)*HD + c0 + 64];
      }
      #pragma unroll
      for (int j=0;j<4;j++){
        float4 av = *(const float4*)&T[(rg+16*j)*132 + k0 + kk];
        fma4(d0[j], av.x, w0[0]); fma4(d1[j], av.x, w1[0]);
        fma4(d0[j], av.y, w0[1]); fma4(d1[j], av.y, w1[1]);
        fma4(d0[j], av.z, w0[2]); fma4(d1[j], av.z, w1[2]);
        fma4(d0[j], av.w, w0[3]); fma4(d1[j], av.w, w1[3]);
      }
    }
  }
  float4 bA = *(const float4*)&b2[c0];
  float4 bB = *(const float4*)&b2[c0+64];
  #pragma unroll
  for (int j=0;j<4;j++){
    int row = r0 + rg + 16*j;
    float4 v0 = d0[j], v1 = d1[j];
    v0.x += bA.x; v0.y += bA.y; v0.z += bA.z; v0.w += bA.w;
    v1.x += bB.x; v1.y += bB.y; v1.z += bB.z; v1.w += bB.w;
    *(float4*)&C[(size_t)row*HD + c0] = v0;
    *(float4*)&C[(size_t)row*HD + c0 + 64] = v1;
  }
}

// score + per-batch sparse softmax (dedup of repeated cells) + scatter
__global__ __launch_bounds__(64) void k_score(const float* __restrict__ Z, const int* __restrict__ mrows,
                                              const int* __restrict__ mcols, float* __restrict__ out){
  __shared__ int rr[64]; __shared__ int cc[64]; __shared__ float red[64];
  int b = blockIdx.x, f = threadIdx.x;
  int i = b*64 + f;
  int rg = mrows[i];
  int row = rg & 1023;
  int col = mcols[i];
  const float4* zr = (const float4*)&Z[(size_t)i*HD];
  const float4* zc = (const float4*)&Z[(size_t)(NPAIR + i)*HD];
  float s = 0.f;
  #pragma unroll
  for (int k=0;k<32;k++){
    float4 a = zr[k], c = zc[k];
    s = fmaf(a.x,c.x, fmaf(a.y,c.y, fmaf(a.z,c.z, fmaf(a.w,c.w, s))));
  }
  rr[f]=row; cc[f]=col; red[f]=s;
  __syncthreads();
  for (int d=32; d>0; d>>=1){
    if (f<d) red[f] = fmaxf(red[f], red[f+d]);
    __syncthreads();
  }
  float m = red[0];
  __syncthreads();
  bool first = true;
  for (int j=0;j<f;j++) if (rr[j]==row && cc[j]==col) first = false;
  float e = expf(s - m);
  red[f] = first ? e : 0.0f;
  __syncthreads();
  for (int d=32; d>0; d>>=1){
    if (f<d) red[f] += red[f+d];
    __syncthreads();
  }
  float denom = red[0];
  out[(size_t)b*1048576 + row*1024 + col] = e / denom;
}

extern "C" void kernel_launch(void* const* d_in, const int* in_sizes, int n_in,
                              void* d_out, int out_size, void* d_ws, size_t ws_size,
                              hipStream_t stream){
  const float* x     = (const float*)d_in[0];
  const int*   ei    = (const int*)d_in[1];
  const int*   mrows = (const int*)d_in[3];
  const int*   mcols = (const int*)d_in[4];
  const float* g0w1  = (const float*)d_in[5];
  const float* g0b1  = (const float*)d_in[6];
  const float* g0w2  = (const float*)d_in[7];
  const float* g0b2  = (const float*)d_in[8];
  const float* gw1   = (const float*)d_in[9];
  const float* gb1   = (const float*)d_in[10];
  const float* gw2   = (const float*)d_in[11];
  const float* gb2   = (const float*)d_in[12];
  const float* bng   = (const float*)d_in[13];
  const float* bnb   = (const float*)d_in[14];
  const float* p0w1  = (const float*)d_in[15];
  const float* p0b1  = (const float*)d_in[16];
  const float* p0w2  = (const float*)d_in[17];
  const float* p0b2  = (const float*)d_in[18];
  const float* pw1   = (const float*)d_in[19];
  const float* pb1   = (const float*)d_in[20];
  const float* pw2   = (const float*)d_in[21];
  const float* pb2   = (const float*)d_in[22];

  float* fw    = (float*)d_ws;
  float* raw0  = fw;                        // N*H
  float* raw1  = fw + 4194304;
  float* raw2  = fw + 8388608;
  float* raw3  = fw + 12582912;
  float* aug   = fw + 16777216;             // 4096*256
  float* pX    = fw + 17825792;             // 4096*128
  float* pY    = fw + 18350080;
  float* pZ    = fw + 18874368;
  float* z8    = fw + 19398656;             // N*8
  float* invdeg= fw + 19660800;             // N
  float* bnsc  = fw + 19693568;             // 4*128
  float* bnsh  = fw + 19694080;
  float* part  = fw + 19694592;             // 4*PSLOT
  float* gsum  = fw + 19956736;             // B*H
  int*   cnt   = (int*)(fw + 19960832);     // N
  int*   fillc = cnt + NND;                 // N
  int*   rowp  = fillc + NND;               // N+1
  int*   csr   = rowp + NND + 1;            // E
  unsigned short* us = (unsigned short*)(fw + 20500000);
  unsigned short* zHi  = us;                // N*H bf16
  unsigned short* zLo  = us + 4194304;
  unsigned short* tHi  = us + 8388608;
  unsigned short* tLo  = us + 12582912;
  unsigned short* WThi = us + 16777216;     // 7*128*128
  unsigned short* WTlo = us + 16891904;
  float* raws[4] = {raw0, raw1, raw2, raw3};

  const int* src = ei;
  const int* dst = ei + NE;

  hipLaunchKernelGGL(k_zero, dim3(2048), dim3(256), 0, stream, (float4*)d_out, out_size/4);
  hipMemsetAsync(cnt, 0, (size_t)(2*NND)*4, stream);   // cnt, fillc
  hipLaunchKernelGGL(k_wsplit, dim3(8,7), dim3(256), 0, stream, g0w2, gw1, gw2, WThi, WTlo);

  hipLaunchKernelGGL(k_count, dim3(NE/256), dim3(256), 0, stream, dst, cnt);
  hipLaunchKernelGGL(k_scan, dim3(1), dim3(1024), 0, stream, cnt, rowp, invdeg);
  hipLaunchKernelGGL(k_fill, dim3(NE/256), dim3(256), 0, stream, src, dst, rowp, fillc, csr);

  // layer 0
  hipLaunchKernelGGL(k_agg8, dim3(NND/256), dim3(256), 0, stream, x, rowp, csr, invdeg, z8);
  hipLaunchKernelGGL(k_gemm8, dim3(NND*HD/256), dim3(256), 0, stream, z8, g0w1, g0b1, tHi, tLo);
  hipLaunchKernelGGL((k_mgemm<1>), dim3(NBLK), dim3(256), 0, stream, tHi, tLo, WThi, WTlo, g0b2,
                     raw0, (unsigned short*)nullptr, (unsigned short*)nullptr, part);
  hipLaunchKernelGGL(k_bn_fin, dim3(128), dim3(256), 0, stream, part, bng, bnb, bnsc, bnsh);

  // layers 1..3
  for (int l=0;l<3;l++){
    hipLaunchKernelGGL(k_agg_bn, dim3(NND), dim3(128), 0, stream, raws[l], rowp, csr, invdeg,
                       bnsc + l*128, bnsh + l*128, zHi, zLo);
    hipLaunchKernelGGL((k_mgemm<0>), dim3(NBLK), dim3(256), 0, stream, zHi, zLo,
                       WThi + (1+l)*16384, WTlo + (1+l)*16384, gb1 + l*128,
                       (float*)nullptr, tHi, tLo, (float*)nullptr);
    hipLaunchKernelGGL((k_mgemm<1>), dim3(NBLK), dim3(256), 0, stream, tHi, tLo,
                       WThi + (4+l)*16384, WTlo + (4+l)*16384, gb2 + l*128,
                       raws[l+1], (unsigned short*)nullptr, (unsigned short*)nullptr, part + (l+1)*PSLOT);
    hipLaunchKernelGGL(k_bn_fin, dim3(128), dim3(256), 0, stream, part + (l+1)*PSLOT, bng + (l+1)*128, bnb + (l+1)*128,
                       bnsc + (l+1)*128, bnsh + (l+1)*128);
  }

  // gpool from part colsums; npool on the fly in build_aug
  hipLaunchKernelGGL(k_gpool, dim3(32), dim3(128), 0, stream, part, bnsc, bnsh, gsum);
  hipLaunchKernelGGL(k_build_aug, dim3(4096), dim3(256), 0, stream, mrows, mcols,
                     raw0, raw1, raw2, raw3, bnsc, bnsh, gsum, aug);

  hipLaunchKernelGGL((k_pol<256>), dim3(64), dim3(256), 0, stream, aug, p0w1, p0b1, p0w2, p0b2, pX);
  hipLaunchKernelGGL((k_pol<128>), dim3(64), dim3(256), 0, stream, pX, pw1, pb1, pw2, pb2, pY);
  hipLaunchKernelGGL((k_pol<128>), dim3(64), dim3(256), 0, stream, pY, pw1 + 16384, pb1 + 128, pw2 + 16384, pb2 + 128, pZ);

  hipLaunchKernelGGL(k_score, dim3(32), dim3(64), 0, stream, pZ, mrows, mcols, (float*)d_out);
}